// Round 13
// baseline (211.286 us; speedup 1.0000x reference)
//
#include <hip/hip_runtime.h>

#define Bn   32
#define HIN  56
#define WIN  56
#define Cc   256
#define HG   28
#define WG   28
#define NPIX (HG*WG)                    // 784

#define GIN_SIZE (Bn*HIN*WIN*Cc)        // 25690112
#define GW_SIZE  (9*Cc*Cc)              // 589824
#define GW_OFF   GIN_SIZE
#define BIAS_OFF (GW_OFF + GW_SIZE)

// workspace layout (bf16 elements)
#define XT_E   (32*57*256*64)           // X_t[b][r][ci][par][m32]
#define GPAD_E (32*29*29*256)           // g_pad[b][iy][jx][co]
#define WTB_E  (9*256*256)              // wt bf16 [tap][ci][co]
#define WS_NEED ((size_t)(XT_E + GPAD_E + WTB_E) * 2)

typedef short bf16x8 __attribute__((ext_vector_type(8)));
typedef float f32x4  __attribute__((ext_vector_type(4)));

__device__ __forceinline__ unsigned short f2bf(float f) {
    return __builtin_bit_cast(unsigned short, (__bf16)f);
}

__device__ __forceinline__ void gload16(const void* g, void* lds) {
    __builtin_amdgcn_global_load_lds(
        (const __attribute__((address_space(1))) unsigned int*)g,
        (__attribute__((address_space(3))) unsigned int*)lds, 16, 0, 0);
}

// hard fence: all vmem+lds retired, then block barrier (rule #18 SGB after)
__device__ __forceinline__ void full_wait_barrier() {
    asm volatile("s_waitcnt vmcnt(0) lgkmcnt(0)" ::: "memory");
    __builtin_amdgcn_s_barrier();
    __builtin_amdgcn_sched_barrier(0);
}
__device__ __forceinline__ void lgkm_wait_barrier() {
    asm volatile("s_waitcnt lgkmcnt(0)" ::: "memory");
    __builtin_amdgcn_s_barrier();
    __builtin_amdgcn_sched_barrier(0);
}
__device__ __forceinline__ void lds_barrier() {   // fallback kernels
    asm volatile("s_waitcnt lgkmcnt(0)" ::: "memory");
    __builtin_amdgcn_s_barrier();
    asm volatile("" ::: "memory");
}

// [row][32] bf16 tile swizzle (fallback grad_in)
__device__ __forceinline__ int swz(int row, int k) {
    int g2 = (k >> 3) ^ (row & 3) ^ ((row >> 2) & 3);
    return row * 32 + (g2 << 3) + (k & 7);
}
// [row][64] bf16 tile swizzle (all 64-wide tiles)
__device__ __forceinline__ int swz64(int row, int k) {
    int gq = ((k >> 3) ^ (row & 7) ^ ((row >> 4) & 7)) & 7;
    return row * 64 + (gq << 3) + (k & 7);
}

__global__ __launch_bounds__(256) void k_zero(float* __restrict__ p, int n) {
    int i = blockIdx.x * 256 + threadIdx.x;
    if (i < n) p[i] = 0.f;
}

// ===========================================================================
// prep: X_t (transposed, parity-split, swizzled) — unchanged (proven R5)
// ===========================================================================
__global__ __launch_bounds__(256) void k_prep_x(
    const float* __restrict__ X, unsigned short* __restrict__ xt)
{
    __shared__ unsigned short L[256 * 64];
    const int t = threadIdx.x;
    const int r = blockIdx.x;     // 0..56
    const int b = blockIdx.y;
    unsigned short* __restrict__ orow = xt + (size_t)((b * 57 + r) * 256) * 64;

    if (r == 56) {
        bf16x8 z = (bf16x8){0,0,0,0,0,0,0,0};
        #pragma unroll
        for (int k = 0; k < 8; ++k)
            *(bf16x8*)&orow[(size_t)(t + 256 * k) * 8] = z;
        return;
    }
    const float* __restrict__ xr = X + (size_t)((b * 56 + r) * 56) * 256;

    #pragma unroll
    for (int a = 0; a < 2; ++a) {
        const int idx = t + 256 * a;
        const int o  = idx >> 6;
        const int ci = (idx & 63) * 4;
        ushort4 ev[4], od[4];
        if (o < 7) {
            float4 xv[8];
            #pragma unroll
            for (int jj = 0; jj < 8; ++jj)
                xv[jj] = *(const float4*)(xr + (size_t)(8 * o + jj) * 256 + ci);
            #pragma unroll
            for (int c = 0; c < 4; ++c) {
                ev[c] = (ushort4){f2bf(((const float*)&xv[0])[c]), f2bf(((const float*)&xv[2])[c]),
                                  f2bf(((const float*)&xv[4])[c]), f2bf(((const float*)&xv[6])[c])};
                od[c] = (ushort4){f2bf(((const float*)&xv[1])[c]), f2bf(((const float*)&xv[3])[c]),
                                  f2bf(((const float*)&xv[5])[c]), f2bf(((const float*)&xv[7])[c])};
            }
        } else {
            #pragma unroll
            for (int c = 0; c < 4; ++c) { ev[c] = (ushort4){0,0,0,0}; od[c] = (ushort4){0,0,0,0}; }
        }
        #pragma unroll
        for (int c = 0; c < 4; ++c) {
            const int row = ci + c;
            const int rb  = (row & 7) ^ ((row >> 4) & 7);
            const int g0  = (o >> 1) ^ rb;
            const int g1  = (4 + (o >> 1)) ^ rb;
            *(ushort4*)&L[row * 64 + g0 * 8 + (o & 1) * 4] = ev[c];
            *(ushort4*)&L[row * 64 + g1 * 8 + (o & 1) * 4] = od[c];
        }
    }
    __syncthreads();
    const int rb = (t & 7) ^ ((t >> 4) & 7);
    #pragma unroll
    for (int G = 0; G < 8; ++G) {
        bf16x8 v = *(bf16x8*)&L[t * 64 + ((G ^ rb)) * 8];
        *(bf16x8*)&orow[t * 64 + G * 8] = v;
    }
}

// g_pad + fused grad_bias with LDS pre-reduction:
// ONE atomic per channel per block (896/address total — R7's disaster was
// un-reduced 7168/address; k_bias's proven-safe level is 392/address).
__global__ __launch_bounds__(256) void k_prep_gpad(
    const float* __restrict__ g, unsigned short* __restrict__ gp,
    float* __restrict__ bias)
{
    __shared__ float R[8][256];
    const int t  = threadIdx.x;
    const int iy = blockIdx.x;    // 0..28
    const int b  = blockIdx.y;
    const int co8 = (t & 31) * 8;
    float bsum[8];
    #pragma unroll
    for (int c = 0; c < 8; ++c) bsum[c] = 0.f;

    for (int jx = (t >> 5); jx < 29; jx += 8) {
        bf16x8 v = (bf16x8){0,0,0,0,0,0,0,0};
        if (iy > 0 && jx > 0) {
            const float* src = g + (size_t)(((b * 28 + iy - 1) * 28) + jx - 1) * 256 + co8;
            float4 a0 = *(const float4*)(src);
            float4 a1 = *(const float4*)(src + 4);
            v = (bf16x8){(short)f2bf(a0.x),(short)f2bf(a0.y),(short)f2bf(a0.z),(short)f2bf(a0.w),
                         (short)f2bf(a1.x),(short)f2bf(a1.y),(short)f2bf(a1.z),(short)f2bf(a1.w)};
            bsum[0] += a0.x; bsum[1] += a0.y; bsum[2] += a0.z; bsum[3] += a0.w;
            bsum[4] += a1.x; bsum[5] += a1.y; bsum[6] += a1.z; bsum[7] += a1.w;
        }
        *(bf16x8*)&gp[(size_t)(((b * 29 + iy) * 29) + jx) * 256 + co8] = v;
    }

    if (iy > 0) {
        #pragma unroll
        for (int c = 0; c < 8; ++c) R[t >> 5][co8 + c] = bsum[c];
        __syncthreads();
        float s = 0.f;
        #pragma unroll
        for (int r = 0; r < 8; ++r) s += R[r][t];
        atomicAdd(bias + t, s);
    }
}

__global__ __launch_bounds__(256) void k_prep_wt(
    const float* __restrict__ w, unsigned short* __restrict__ wb)
{
    const size_t i8 = (size_t)(blockIdx.x * 256 + threadIdx.x) * 8;
    float4 a0 = *(const float4*)(w + i8);
    float4 a1 = *(const float4*)(w + i8 + 4);
    bf16x8 v = (bf16x8){(short)f2bf(a0.x),(short)f2bf(a0.y),(short)f2bf(a0.z),(short)f2bf(a0.w),
                        (short)f2bf(a1.x),(short)f2bf(a1.y),(short)f2bf(a1.z),(short)f2bf(a1.w)};
    *(bf16x8*)&wb[i8] = v;
}

// ===========================================================================
// grad_in fast (EXACT R8 version, proven ~53 µs): grid (196,2,4),
// At[2]+Bt[2] gload-dbuf, 1 barrier/chunk, 64KB LDS -> 2 blocks/CU.
// ===========================================================================
__global__ __launch_bounds__(256, 2) void k_grad_in_f(
    const unsigned short* __restrict__ gpad,
    const unsigned short* __restrict__ wtb,
    float* __restrict__ out)
{
    __shared__ unsigned short At[2][128 * 64];
    __shared__ unsigned short Bt[2][128 * 64];

    const int t = threadIdx.x;
    const int l = t & 63, wave = t >> 6;
    const int mbase = (wave & 1) * 64, nbase = (wave >> 1) * 64;
    const int q = l >> 4, r16 = l & 15;
    const int mtile = blockIdx.x, ntile = blockIdx.y, cls = blockIdx.z;
    const int dy = cls >> 1, dx = cls & 1;
    const int nky = dy ? 1 : 2, nkx = dx ? 1 : 2;
    const bool nkx2 = (nkx == 2);
    const int NC = nky * nkx * 4;

    int gsv[4], ab[4], aiy[4], ajx[4];
    #pragma unroll
    for (int u = 0; u < 4; ++u) {
        const int row = u * 32 + (t >> 3);
        gsv[u] = (t & 7) ^ (row & 7) ^ ((row >> 4) & 7);
        const int P = mtile * 128 + row;
        ab[u] = P / NPIX;
        const int rem = P % NPIX;
        aiy[u] = rem / WG; ajx[u] = rem % WG;
    }

    f32x4 acc[4][4];
    #pragma unroll
    for (int a = 0; a < 4; ++a)
        #pragma unroll
        for (int b = 0; b < 4; ++b) acc[a][b] = (f32x4){0.f, 0.f, 0.f, 0.f};

    int aoff[2][4], boff[2][4];
    #pragma unroll
    for (int kk = 0; kk < 2; ++kk)
        #pragma unroll
        for (int mf = 0; mf < 4; ++mf) {
            aoff[kk][mf] = swz64(mbase + mf * 16 + r16, kk * 32 + q * 8);
            boff[kk][mf] = swz64(nbase + mf * 16 + r16, kk * 32 + q * 8);
        }

    auto prefetch = [&](int c, int buf) {
        const int tapi = c >> 2, co0 = (c & 3) << 6;
        const int ty = nkx2 ? (tapi >> 1) : tapi;
        const int tx = nkx2 ? (tapi & 1) : 0;
        const int di = dy ? 0 : (ty ? 0 : -1);
        const int dj = dx ? 0 : (tx ? 0 : -1);
        const int krow = dy ? 1 : (ty ? 0 : 2);
        const int kcol = dx ? 1 : (tx ? 0 : 2);
        const unsigned short* wb2 = wtb + (size_t)((krow * 3 + kcol) * 256 + ntile * 128) * 256 + co0;
        #pragma unroll
        for (int u = 0; u < 4; ++u) {
            const unsigned short* as2 = gpad
                + (size_t)(((ab[u] * 29 + aiy[u] + di + 1) * 29) + ajx[u] + dj + 1) * 256
                + 8 * gsv[u] + co0;
            gload16(as2, &At[buf][u * 2048 + t * 8]);
            gload16(wb2 + (size_t)(u * 32 + (t >> 3)) * 256 + 8 * gsv[u], &Bt[buf][u * 2048 + t * 8]);
        }
    };

    prefetch(0, 0);

    #pragma unroll 1
    for (int cc = 0; cc < NC; ++cc) {
        const int p = cc & 1, n = cc + 1;
        full_wait_barrier();                 // chunk cc resident; MFMA(cc-1) done everywhere
        if (n < NC) prefetch(n, n & 1);      // fly across MFMA(cc)
        __builtin_amdgcn_sched_barrier(0);

        #pragma unroll
        for (int kk = 0; kk < 2; ++kk) {
            bf16x8 af[4], bf[4];
            #pragma unroll
            for (int mf = 0; mf < 4; ++mf) af[mf] = *(const bf16x8*)&At[p][aoff[kk][mf]];
            #pragma unroll
            for (int nf = 0; nf < 4; ++nf) bf[nf] = *(const bf16x8*)&Bt[p][boff[kk][nf]];
            #pragma unroll
            for (int mf = 0; mf < 4; ++mf)
                #pragma unroll
                for (int nf = 0; nf < 4; ++nf)
                    acc[mf][nf] = __builtin_amdgcn_mfma_f32_16x16x32_bf16(
                        af[mf], bf[nf], acc[mf][nf], 0, 0, 0);
        }
    }

    #pragma unroll
    for (int mf = 0; mf < 4; ++mf) {
        #pragma unroll
        for (int rr = 0; rr < 4; ++rr) {
            const int P   = mtile * 128 + mbase + mf * 16 + q * 4 + rr;
            const int b   = P / NPIX;
            const int rem = P % NPIX;
            const int iy  = rem / WG, jx = rem % WG;
            const int y = 2 * iy + dy, x = 2 * jx + dx;
            float* orow = out + (size_t)((b * HIN + y) * WIN + x) * Cc
                              + ntile * 128 + nbase + r16;
            #pragma unroll
            for (int nf = 0; nf < 4; ++nf) orow[nf * 16] = acc[mf][nf][rr];
        }
    }
}

// ===========================================================================
// grad_wt fast (EXACT R8 version, confirmed 90 µs): A dbuf gload, B single
// reg-staged; 2 barriers/chunk; batch->XCD remap. 48KB LDS -> 3 blocks/CU.
// ===========================================================================
__global__ __launch_bounds__(256, 3) void k_grad_wt_f(
    const unsigned short* __restrict__ xt,
    const unsigned short* __restrict__ gpad,
    float* __restrict__ gw)
{
    __shared__ unsigned short At[2][128 * 64];
    __shared__ unsigned short Bt[128 * 64];

    const int t = threadIdx.x;
    const int l = t & 63, wave = t >> 6;
    const int mbase = (wave & 1) * 64, nbase = (wave >> 1) * 64;
    const int q = l >> 4, r16 = l & 15;

    const int L   = blockIdx.x;           // 0..1151
    const int xcd = L & 7, idx = L >> 3;
    const int b   = xcd + 8 * (idx / 36);
    const int tt  = idx % 36;
    const int tap = tt >> 2, tile = tt & 3;
    const int tci = (tile >> 1) * 128, tco = (tile & 1) * 128;
    const int ki = tap / 3, kj = tap % 3;
    const int par = (kj == 1);
    const int jsh = (kj == 2);

    const unsigned short* axp[4];
    #pragma unroll
    for (int u = 0; u < 4; ++u) {
        const int row = u * 32 + (t >> 3);
        const int gs  = (t & 7) ^ (row & 7) ^ ((row >> 4) & 7);
        const int r0  = ki + 2 * (gs >> 2);
        axp[u] = xt + (size_t)((b * 57 + r0) * 256 + tci + row) * 64 + par * 32 + (gs & 3) * 8;
    }

    const int o   = t >> 5;
    const int rs  = o >> 2;
    const int mo  = (o & 3) * 8;
    const int co4 = (t & 31) * 4;

    uint2 br[8];
    auto load_breg = [&](int cc) {
        const int i = 2 * cc + rs;
        const int base_i = (b * 29 + i + 1) * 29;
        #pragma unroll
        for (int jj = 0; jj < 8; ++jj) {
            const int j = mo + jj - jsh;
            uint2 v; v.x = 0u; v.y = 0u;
            if (j <= 27) v = *(const uint2*)(gpad + (size_t)(base_i + j + 1) * 256 + tco + co4);
            br[jj] = v;
        }
    };

    f32x4 acc[4][4];
    #pragma unroll
    for (int a = 0; a < 4; ++a)
        #pragma unroll
        for (int c = 0; c < 4; ++c) acc[a][c] = (f32x4){0.f, 0.f, 0.f, 0.f};

    int aoff[2][4], boff[2][4];
    #pragma unroll
    for (int kk = 0; kk < 2; ++kk)
        #pragma unroll
        for (int mf = 0; mf < 4; ++mf) {
            aoff[kk][mf] = swz64(mbase + mf * 16 + r16, kk * 32 + q * 8);
            boff[kk][mf] = swz64(nbase + mf * 16 + r16, kk * 32 + q * 8);
        }

    #pragma unroll
    for (int u = 0; u < 4; ++u) { gload16(axp[u], &At[0][u * 2048 + t * 8]); axp[u] += 65536; }
    load_breg(0);

    #pragma unroll 1
    for (int cc = 0; cc < 14; ++cc) {
        const int p = cc & 1, n = cc + 1;
        full_wait_barrier();                 // At[p]+br resident; MFMA(cc-1) done
        if (n < 14) {
            #pragma unroll
            for (int u = 0; u < 4; ++u) { gload16(axp[u], &At[n & 1][u * 2048 + t * 8]); axp[u] += 65536; }
        }
        __builtin_amdgcn_sched_barrier(0);
        {
            const unsigned short* bs = (const unsigned short*)br;
            #pragma unroll
            for (int c = 0; c < 4; ++c) {
                bf16x8 wv;
                #pragma unroll
                for (int jj = 0; jj < 8; ++jj) wv[jj] = (short)bs[jj * 4 + c];
                const int row  = co4 + c;
                const int gpos = o ^ (row & 7) ^ ((row >> 4) & 7);
                *(bf16x8*)&Bt[row * 64 + gpos * 8] = wv;
            }
        }
        if (n < 14) load_breg(n);            // fly across MFMA(cc)
        __builtin_amdgcn_sched_barrier(0);
        lgkm_wait_barrier();                 // Bt visible

        #pragma unroll
        for (int kk = 0; kk < 2; ++kk) {
            bf16x8 af[4], bfr[4];
            #pragma unroll
            for (int mf = 0; mf < 4; ++mf) af[mf]  = *(const bf16x8*)&At[p][aoff[kk][mf]];
            #pragma unroll
            for (int nf = 0; nf < 4; ++nf) bfr[nf] = *(const bf16x8*)&Bt[boff[kk][nf]];
            #pragma unroll
            for (int mf = 0; mf < 4; ++mf)
                #pragma unroll
                for (int nf = 0; nf < 4; ++nf)
                    acc[mf][nf] = __builtin_amdgcn_mfma_f32_16x16x32_bf16(
                        af[mf], bfr[nf], acc[mf][nf], 0, 0, 0);
        }
    }

    #pragma unroll
    for (int mf = 0; mf < 4; ++mf) {
        #pragma unroll
        for (int rr = 0; rr < 4; ++rr) {
            const int cirow = tci + mbase + mf * 16 + q * 4 + rr;
            float* dst = gw + (size_t)(tap * Cc + cirow) * Cc + tco + nbase + r16;
            #pragma unroll
            for (int nf = 0; nf < 4; ++nf) atomicAdd(dst + nf * 16, acc[mf][nf][rr]);
        }
    }
}

// grad_bias (fallback path only): 392 blocks x 64 pixels; thread t sums co=t.
__global__ __launch_bounds__(256) void k_bias(
    const float* __restrict__ g, float* __restrict__ bias)
{
    const int t = threadIdx.x;
    const float* base = g + (size_t)blockIdx.x * 64 * Cc;
    float acc = 0.f;
    #pragma unroll 8
    for (int p = 0; p < 64; ++p) acc += base[(size_t)p * Cc + t];
    atomicAdd(bias + t, acc);
}

// ===========================================================================
// fallback kernels (R4, proven) — used only when ws_size is insufficient
// ===========================================================================
__global__ __launch_bounds__(256) void k_grad_in_fb(
    const float* __restrict__ g, const float* __restrict__ wt, float* __restrict__ out)
{
    __shared__ unsigned short ga[128 * 32];
    __shared__ unsigned short wb[128 * 32];
    const int t = threadIdx.x;
    const int l = t & 63, wave = t >> 6;
    const int mbase = (wave & 1) * 64, nbase = (wave >> 1) * 64;
    const int q = l >> 4, r16 = l & 15;
    const int mtile = blockIdx.x, ntile = blockIdx.y, cls = blockIdx.z;
    const int dy = cls >> 1, dx = cls & 1;
    const int sp = t >> 1, sc = (t & 1) * 16;
    const int P_s = mtile * 128 + sp;
    const int b_s = P_s / NPIX;
    const int rem_s = P_s % NPIX;
    const int iy_s = rem_s / WG, jx_s = rem_s % WG;
    const int sci = ntile * 128 + sp;
    f32x4 acc[4][4];
    #pragma unroll
    for (int a = 0; a < 4; ++a)
        #pragma unroll
        for (int b = 0; b < 4; ++b) acc[a][b] = (f32x4){0.f,0.f,0.f,0.f};
    int aoff[4], boff[4];
    #pragma unroll
    for (int mf = 0; mf < 4; ++mf) aoff[mf] = swz(mbase + mf * 16 + r16, q * 8);
    #pragma unroll
    for (int nf = 0; nf < 4; ++nf) boff[nf] = swz(nbase + nf * 16 + r16, q * 8);
    const int nky = dy ? 1 : 2, nkx = dx ? 1 : 2;
    for (int ty = 0; ty < nky; ++ty) {
        const int di = dy ? 0 : (ty == 0 ? -1 : 0);
        const int krow = dy ? 1 : (ty == 0 ? 2 : 0);
        for (int tx = 0; tx < nkx; ++tx) {
            const int dj = dx ? 0 : (tx == 0 ? -1 : 0);
            const int kcol = dx ? 1 : (tx == 0 ? 2 : 0);
            const int gi = iy_s + di, gj = jx_s + dj;
            const bool valid = (gi >= 0) && (gj >= 0);
            const float* __restrict__ gsrc = g + (size_t)((b_s * HG + gi) * WG + gj) * Cc + sc;
            const float* __restrict__ wsrc = wt + (size_t)((krow * 3 + kcol) * Cc + sci) * Cc + sc;
            float4 av[4], bv[4];
            #pragma unroll
            for (int u = 0; u < 4; ++u) {
                av[u] = make_float4(0.f,0.f,0.f,0.f);
                if (valid) av[u] = *(const float4*)(gsrc + u * 4);
                bv[u] = *(const float4*)(wsrc + u * 4);
            }
            #pragma unroll 1
            for (int co0 = 0; co0 < Cc; co0 += 32) {
                ushort4 ua[4], ub[4];
                #pragma unroll
                for (int u = 0; u < 4; ++u) {
                    ua[u] = (ushort4){f2bf(av[u].x), f2bf(av[u].y), f2bf(av[u].z), f2bf(av[u].w)};
                    ub[u] = (ushort4){f2bf(bv[u].x), f2bf(bv[u].y), f2bf(bv[u].z), f2bf(bv[u].w)};
                }
                if (co0 + 32 < Cc) {
                    #pragma unroll
                    for (int u = 0; u < 4; ++u) {
                        float4 a2 = make_float4(0.f,0.f,0.f,0.f);
                        if (valid) a2 = *(const float4*)(gsrc + co0 + 32 + u * 4);
                        float4 b2 = *(const float4*)(wsrc + co0 + 32 + u * 4);
                        av[u] = a2; bv[u] = b2;
                    }
                }
                lds_barrier();
                #pragma unroll
                for (int u = 0; u < 4; ++u) {
                    *(ushort4*)&ga[swz(sp, sc + u * 4)] = ua[u];
                    *(ushort4*)&wb[swz(sp, sc + u * 4)] = ub[u];
                }
                lds_barrier();
                bf16x8 af[4], bf[4];
                #pragma unroll
                for (int mf = 0; mf < 4; ++mf) af[mf] = *(const bf16x8*)&ga[aoff[mf]];
                #pragma unroll
                for (int nf = 0; nf < 4; ++nf) bf[nf] = *(const bf16x8*)&wb[boff[nf]];
                #pragma unroll
                for (int mf = 0; mf < 4; ++mf)
                    #pragma unroll
                    for (int nf = 0; nf < 4; ++nf)
                        acc[mf][nf] = __builtin_amdgcn_mfma_f32_16x16x32_bf16(
                            af[mf], bf[nf], acc[mf][nf], 0, 0, 0);
            }
        }
    }
    #pragma unroll
    for (int mf = 0; mf < 4; ++mf)
        #pragma unroll
        for (int rr = 0; rr < 4; ++rr) {
            const int P = mtile * 128 + mbase + mf * 16 + q * 4 + rr;
            const int b = P / NPIX;
            const int rem = P % NPIX;
            const int iy = rem / WG, jx = rem % WG;
            const int y = 2 * iy + dy, x = 2 * jx + dx;
            float* orow = out + (size_t)((b * HIN + y) * WIN + x) * Cc + ntile * 128 + nbase + r16;
            #pragma unroll
            for (int nf = 0; nf < 4; ++nf) orow[nf * 16] = acc[mf][nf][rr];
        }
}

__global__ __launch_bounds__(256) void k_grad_wt_fb(
    const float* __restrict__ g, const float* __restrict__ inp, float* __restrict__ gw)
{
    __shared__ unsigned short xa[128 * 64];
    __shared__ unsigned short xg[128 * 64];
    const int t = threadIdx.x;
    const int l = t & 63, wave = t >> 6;
    const int mbase = (wave & 1) * 64, nbase = (wave >> 1) * 64;
    const int q = l >> 4, r16 = l & 15;
    const int tci = (blockIdx.x >> 1) * 128, tco = (blockIdx.x & 1) * 128;
    const int tap = blockIdx.y;
    const int ki = tap / 3, kj = tap % 3;
    const int b = blockIdx.z;
    const int pg = t >> 5, p0 = pg * 8, c4 = (t & 31) * 4;
    f32x4 acc[4][4];
    #pragma unroll
    for (int a = 0; a < 4; ++a)
        #pragma unroll
        for (int c = 0; c < 4; ++c) acc[a][c] = (f32x4){0.f,0.f,0.f,0.f};
    int aoff[2][4], boff[2][4];
    #pragma unroll
    for (int kk = 0; kk < 2; ++kk)
        #pragma unroll
        for (int mf = 0; mf < 4; ++mf) {
            aoff[kk][mf] = swz64(mbase + mf * 16 + r16, kk * 32 + q * 8);
            boff[kk][mf] = swz64(nbase + mf * 16 + r16, kk * 32 + q * 8);
        }
    const float* __restrict__ gb = g + (size_t)b * NPIX * Cc;
    const float* __restrict__ ib = inp + (size_t)b * HIN * WIN * Cc;
    float4 xr[8], gr[8];
    auto load_chunk = [&](int cc) {
        #pragma unroll
        for (int j = 0; j < 8; ++j) {
            const int p = cc * 64 + p0 + j;
            const int i = p / WG, jw = p % WG;
            const int r = ki + 2 * i, s = kj + 2 * jw;
            const bool vx = (p < NPIX) && (r < HIN) && (s < WIN);
            const bool vg = (p < NPIX);
            float4 xv = make_float4(0.f,0.f,0.f,0.f), gv = xv;
            if (vx) xv = *(const float4*)(ib + (size_t)(r * WIN + s) * Cc + tci + c4);
            if (vg) gv = *(const float4*)(gb + (size_t)p * Cc + tco + c4);
            xr[j] = xv; gr[j] = gv;
        }
    };
    load_chunk(0);
    #pragma unroll 1
    for (int cc = 0; cc < 13; ++cc) {
        bf16x8 wx[4], wg[4];
        #pragma unroll
        for (int j = 0; j < 8; ++j) {
            wx[0][j] = (short)f2bf(xr[j].x); wx[1][j] = (short)f2bf(xr[j].y);
            wx[2][j] = (short)f2bf(xr[j].z); wx[3][j] = (short)f2bf(xr[j].w);
            wg[0][j] = (short)f2bf(gr[j].x); wg[1][j] = (short)f2bf(gr[j].y);
            wg[2][j] = (short)f2bf(gr[j].z); wg[3][j] = (short)f2bf(gr[j].w);
        }
        if (cc + 1 < 13) load_chunk(cc + 1);
        lds_barrier();
        #pragma unroll
        for (int c = 0; c < 4; ++c) {
            *(bf16x8*)&xa[swz64(c4 + c, p0)] = wx[c];
            *(bf16x8*)&xg[swz64(c4 + c, p0)] = wg[c];
        }
        lds_barrier();
        #pragma unroll
        for (int kk = 0; kk < 2; ++kk) {
            bf16x8 af[4], bfr[4];
            #pragma unroll
            for (int mf = 0; mf < 4; ++mf) af[mf] = *(const bf16x8*)&xa[aoff[kk][mf]];
            #pragma unroll
            for (int nf = 0; nf < 4; ++nf) bfr[nf] = *(const bf16x8*)&xg[boff[kk][nf]];
            #pragma unroll
            for (int mf = 0; mf < 4; ++mf)
                #pragma unroll
                for (int nf = 0; nf < 4; ++nf)
                    acc[mf][nf] = __builtin_amdgcn_mfma_f32_16x16x32_bf16(
                        af[mf], bfr[nf], acc[mf][nf], 0, 0, 0);
        }
    }
    #pragma unroll
    for (int mf = 0; mf < 4; ++mf)
        #pragma unroll
        for (int rr = 0; rr < 4; ++rr) {
            const int cirow = tci + mbase + mf * 16 + q * 4 + rr;
            float* dst = gw + (size_t)(tap * Cc + cirow) * Cc + tco + nbase + r16;
            #pragma unroll
            for (int nf = 0; nf < 4; ++nf) atomicAdd(dst + nf * 16, acc[mf][nf][rr]);
        }
}

extern "C" void kernel_launch(void* const* d_in, const int* in_sizes, int n_in,
                              void* d_out, int out_size, void* d_ws, size_t ws_size,
                              hipStream_t stream) {
    const float* g   = (const float*)d_in[0];   // grad_output [32,28,28,256]
    const float* inp = (const float*)d_in[1];   // inputs      [32,56,56,256]
    const float* wt  = (const float*)d_in[2];   // kernels     [3,3,256,256]
    float* out = (float*)d_out;

    const int nzero = GW_SIZE + 256;
    k_zero<<<(nzero + 255) / 256, 256, 0, stream>>>(out + GW_OFF, nzero);

    if (ws_size >= WS_NEED) {
        unsigned short* xt  = (unsigned short*)d_ws;
        unsigned short* gp  = xt + XT_E;
        unsigned short* wtb = gp + GPAD_E;
        k_prep_x   <<<dim3(57, 32), 256, 0, stream>>>(inp, xt);
        k_prep_gpad<<<dim3(29, 32), 256, 0, stream>>>(g, gp, out + BIAS_OFF);
        k_prep_wt  <<<WTB_E / 2048, 256, 0, stream>>>(wt, wtb);
        k_grad_in_f<<<dim3(196, 2, 4), 256, 0, stream>>>(gp, wtb, out);
        k_grad_wt_f<<<1152, 256, 0, stream>>>(xt, gp, out + GW_OFF);
    } else {
        k_grad_in_fb<<<dim3(196, 2, 4), 256, 0, stream>>>(g, wt, out);
        k_grad_wt_fb<<<dim3(4, 9, 32), 256, 0, stream>>>(g, inp, out + GW_OFF);
        k_bias<<<392, 256, 0, stream>>>(g, out + BIAS_OFF);
    }
}

// Round 14
// 206.161 us; speedup vs baseline: 1.0249x; 1.0249x over previous
//
#include <hip/hip_runtime.h>

#define Bn   32
#define HIN  56
#define WIN  56
#define Cc   256
#define HG   28
#define WG   28
#define NPIX (HG*WG)                    // 784

#define GIN_SIZE (Bn*HIN*WIN*Cc)        // 25690112
#define GW_SIZE  (9*Cc*Cc)              // 589824
#define GW_OFF   GIN_SIZE
#define BIAS_OFF (GW_OFF + GW_SIZE)

// workspace layout (bf16 elements)
#define XT_E   (32*57*256*64)           // X_t[b][r][ci][par][m32]
#define GPAD_E (32*29*29*256)           // g_pad[b][iy][jx][co]
#define WTB_E  (9*256*256)              // wt bf16 [tap][ci][co]
#define WS_NEED ((size_t)(XT_E + GPAD_E + WTB_E) * 2)
#define GP_ROWS (32*29*29)              // 26912

typedef short bf16x8 __attribute__((ext_vector_type(8)));
typedef float f32x4  __attribute__((ext_vector_type(4)));

__device__ __forceinline__ unsigned short f2bf(float f) {
    return __builtin_bit_cast(unsigned short, (__bf16)f);
}
__device__ __forceinline__ float bf2f(unsigned short u) {
    union { unsigned int u; float f; } v; v.u = ((unsigned int)u) << 16;
    return v.f;
}

__device__ __forceinline__ void gload16(const void* g, void* lds) {
    __builtin_amdgcn_global_load_lds(
        (const __attribute__((address_space(1))) unsigned int*)g,
        (__attribute__((address_space(3))) unsigned int*)lds, 16, 0, 0);
}

// hard fence: all vmem+lds retired, then block barrier (rule #18 SGB after)
__device__ __forceinline__ void full_wait_barrier() {
    asm volatile("s_waitcnt vmcnt(0) lgkmcnt(0)" ::: "memory");
    __builtin_amdgcn_s_barrier();
    __builtin_amdgcn_sched_barrier(0);
}
__device__ __forceinline__ void lgkm_wait_barrier() {
    asm volatile("s_waitcnt lgkmcnt(0)" ::: "memory");
    __builtin_amdgcn_s_barrier();
    __builtin_amdgcn_sched_barrier(0);
}
__device__ __forceinline__ void lds_barrier() {   // fallback kernels
    asm volatile("s_waitcnt lgkmcnt(0)" ::: "memory");
    __builtin_amdgcn_s_barrier();
    asm volatile("" ::: "memory");
}

// [row][32] bf16 tile swizzle (fallback grad_in)
__device__ __forceinline__ int swz(int row, int k) {
    int g2 = (k >> 3) ^ (row & 3) ^ ((row >> 2) & 3);
    return row * 32 + (g2 << 3) + (k & 7);
}
// [row][64] bf16 tile swizzle (all 64-wide tiles)
__device__ __forceinline__ int swz64(int row, int k) {
    int gq = ((k >> 3) ^ (row & 7) ^ ((row >> 4) & 7)) & 7;
    return row * 64 + (gq << 3) + (k & 7);
}

__global__ __launch_bounds__(256) void k_zero(float* __restrict__ p, int n) {
    int i = blockIdx.x * 256 + threadIdx.x;
    if (i < n) p[i] = 0.f;
}

// ===========================================================================
// prep: X_t (transposed, parity-split, swizzled) — unchanged (proven R5)
// ===========================================================================
__global__ __launch_bounds__(256) void k_prep_x(
    const float* __restrict__ X, unsigned short* __restrict__ xt)
{
    __shared__ unsigned short L[256 * 64];
    const int t = threadIdx.x;
    const int r = blockIdx.x;     // 0..56
    const int b = blockIdx.y;
    unsigned short* __restrict__ orow = xt + (size_t)((b * 57 + r) * 256) * 64;

    if (r == 56) {
        bf16x8 z = (bf16x8){0,0,0,0,0,0,0,0};
        #pragma unroll
        for (int k = 0; k < 8; ++k)
            *(bf16x8*)&orow[(size_t)(t + 256 * k) * 8] = z;
        return;
    }
    const float* __restrict__ xr = X + (size_t)((b * 56 + r) * 56) * 256;

    #pragma unroll
    for (int a = 0; a < 2; ++a) {
        const int idx = t + 256 * a;
        const int o  = idx >> 6;
        const int ci = (idx & 63) * 4;
        ushort4 ev[4], od[4];
        if (o < 7) {
            float4 xv[8];
            #pragma unroll
            for (int jj = 0; jj < 8; ++jj)
                xv[jj] = *(const float4*)(xr + (size_t)(8 * o + jj) * 256 + ci);
            #pragma unroll
            for (int c = 0; c < 4; ++c) {
                ev[c] = (ushort4){f2bf(((const float*)&xv[0])[c]), f2bf(((const float*)&xv[2])[c]),
                                  f2bf(((const float*)&xv[4])[c]), f2bf(((const float*)&xv[6])[c])};
                od[c] = (ushort4){f2bf(((const float*)&xv[1])[c]), f2bf(((const float*)&xv[3])[c]),
                                  f2bf(((const float*)&xv[5])[c]), f2bf(((const float*)&xv[7])[c])};
            }
        } else {
            #pragma unroll
            for (int c = 0; c < 4; ++c) { ev[c] = (ushort4){0,0,0,0}; od[c] = (ushort4){0,0,0,0}; }
        }
        #pragma unroll
        for (int c = 0; c < 4; ++c) {
            const int row = ci + c;
            const int rb  = (row & 7) ^ ((row >> 4) & 7);
            const int g0  = (o >> 1) ^ rb;
            const int g1  = (4 + (o >> 1)) ^ rb;
            *(ushort4*)&L[row * 64 + g0 * 8 + (o & 1) * 4] = ev[c];
            *(ushort4*)&L[row * 64 + g1 * 8 + (o & 1) * 4] = od[c];
        }
    }
    __syncthreads();
    const int rb = (t & 7) ^ ((t >> 4) & 7);
    #pragma unroll
    for (int G = 0; G < 8; ++G) {
        bf16x8 v = *(bf16x8*)&L[t * 64 + ((G ^ rb)) * 8];
        *(bf16x8*)&orow[t * 64 + G * 8] = v;
    }
}

// g_pad[b][iy][jx][co] = (iy==0||jx==0) ? 0 : bf16(g[b][iy-1][jx-1][co])
// (pure R5/R8 form — no bias atomics)
__global__ __launch_bounds__(256) void k_prep_gpad(
    const float* __restrict__ g, unsigned short* __restrict__ gp)
{
    const int t  = threadIdx.x;
    const int iy = blockIdx.x;    // 0..28
    const int b  = blockIdx.y;
    const int co8 = (t & 31) * 8;
    for (int jx = (t >> 5); jx < 29; jx += 8) {
        bf16x8 v = (bf16x8){0,0,0,0,0,0,0,0};
        if (iy > 0 && jx > 0) {
            const float* src = g + (size_t)(((b * 28 + iy - 1) * 28) + jx - 1) * 256 + co8;
            float4 a0 = *(const float4*)(src);
            float4 a1 = *(const float4*)(src + 4);
            v = (bf16x8){(short)f2bf(a0.x),(short)f2bf(a0.y),(short)f2bf(a0.z),(short)f2bf(a0.w),
                         (short)f2bf(a1.x),(short)f2bf(a1.y),(short)f2bf(a1.z),(short)f2bf(a1.w)};
        }
        *(bf16x8*)&gp[(size_t)(((b * 29 + iy) * 29) + jx) * 256 + co8] = v;
    }
}

__global__ __launch_bounds__(256) void k_prep_wt(
    const float* __restrict__ w, unsigned short* __restrict__ wb)
{
    const size_t i8 = (size_t)(blockIdx.x * 256 + threadIdx.x) * 8;
    float4 a0 = *(const float4*)(w + i8);
    float4 a1 = *(const float4*)(w + i8 + 4);
    bf16x8 v = (bf16x8){(short)f2bf(a0.x),(short)f2bf(a0.y),(short)f2bf(a0.z),(short)f2bf(a0.w),
                        (short)f2bf(a1.x),(short)f2bf(a1.y),(short)f2bf(a1.z),(short)f2bf(a1.w)};
    *(bf16x8*)&wb[i8] = v;
}

// ===========================================================================
// grad_in fast (EXACT R8 version, proven ~53 µs): grid (196,2,4),
// At[2]+Bt[2] gload-dbuf, 1 barrier/chunk, 64KB LDS -> 2 blocks/CU.
// ===========================================================================
__global__ __launch_bounds__(256, 2) void k_grad_in_f(
    const unsigned short* __restrict__ gpad,
    const unsigned short* __restrict__ wtb,
    float* __restrict__ out)
{
    __shared__ unsigned short At[2][128 * 64];
    __shared__ unsigned short Bt[2][128 * 64];

    const int t = threadIdx.x;
    const int l = t & 63, wave = t >> 6;
    const int mbase = (wave & 1) * 64, nbase = (wave >> 1) * 64;
    const int q = l >> 4, r16 = l & 15;
    const int mtile = blockIdx.x, ntile = blockIdx.y, cls = blockIdx.z;
    const int dy = cls >> 1, dx = cls & 1;
    const int nky = dy ? 1 : 2, nkx = dx ? 1 : 2;
    const bool nkx2 = (nkx == 2);
    const int NC = nky * nkx * 4;

    int gsv[4], ab[4], aiy[4], ajx[4];
    #pragma unroll
    for (int u = 0; u < 4; ++u) {
        const int row = u * 32 + (t >> 3);
        gsv[u] = (t & 7) ^ (row & 7) ^ ((row >> 4) & 7);
        const int P = mtile * 128 + row;
        ab[u] = P / NPIX;
        const int rem = P % NPIX;
        aiy[u] = rem / WG; ajx[u] = rem % WG;
    }

    f32x4 acc[4][4];
    #pragma unroll
    for (int a = 0; a < 4; ++a)
        #pragma unroll
        for (int b = 0; b < 4; ++b) acc[a][b] = (f32x4){0.f, 0.f, 0.f, 0.f};

    int aoff[2][4], boff[2][4];
    #pragma unroll
    for (int kk = 0; kk < 2; ++kk)
        #pragma unroll
        for (int mf = 0; mf < 4; ++mf) {
            aoff[kk][mf] = swz64(mbase + mf * 16 + r16, kk * 32 + q * 8);
            boff[kk][mf] = swz64(nbase + mf * 16 + r16, kk * 32 + q * 8);
        }

    auto prefetch = [&](int c, int buf) {
        const int tapi = c >> 2, co0 = (c & 3) << 6;
        const int ty = nkx2 ? (tapi >> 1) : tapi;
        const int tx = nkx2 ? (tapi & 1) : 0;
        const int di = dy ? 0 : (ty ? 0 : -1);
        const int dj = dx ? 0 : (tx ? 0 : -1);
        const int krow = dy ? 1 : (ty ? 0 : 2);
        const int kcol = dx ? 1 : (tx ? 0 : 2);
        const unsigned short* wb2 = wtb + (size_t)((krow * 3 + kcol) * 256 + ntile * 128) * 256 + co0;
        #pragma unroll
        for (int u = 0; u < 4; ++u) {
            const unsigned short* as2 = gpad
                + (size_t)(((ab[u] * 29 + aiy[u] + di + 1) * 29) + ajx[u] + dj + 1) * 256
                + 8 * gsv[u] + co0;
            gload16(as2, &At[buf][u * 2048 + t * 8]);
            gload16(wb2 + (size_t)(u * 32 + (t >> 3)) * 256 + 8 * gsv[u], &Bt[buf][u * 2048 + t * 8]);
        }
    };

    prefetch(0, 0);

    #pragma unroll 1
    for (int cc = 0; cc < NC; ++cc) {
        const int p = cc & 1, n = cc + 1;
        full_wait_barrier();                 // chunk cc resident; MFMA(cc-1) done everywhere
        if (n < NC) prefetch(n, n & 1);      // fly across MFMA(cc)
        __builtin_amdgcn_sched_barrier(0);

        #pragma unroll
        for (int kk = 0; kk < 2; ++kk) {
            bf16x8 af[4], bf[4];
            #pragma unroll
            for (int mf = 0; mf < 4; ++mf) af[mf] = *(const bf16x8*)&At[p][aoff[kk][mf]];
            #pragma unroll
            for (int nf = 0; nf < 4; ++nf) bf[nf] = *(const bf16x8*)&Bt[p][boff[kk][nf]];
            #pragma unroll
            for (int mf = 0; mf < 4; ++mf)
                #pragma unroll
                for (int nf = 0; nf < 4; ++nf)
                    acc[mf][nf] = __builtin_amdgcn_mfma_f32_16x16x32_bf16(
                        af[mf], bf[nf], acc[mf][nf], 0, 0, 0);
        }
    }

    #pragma unroll
    for (int mf = 0; mf < 4; ++mf) {
        #pragma unroll
        for (int rr = 0; rr < 4; ++rr) {
            const int P   = mtile * 128 + mbase + mf * 16 + q * 4 + rr;
            const int b   = P / NPIX;
            const int rem = P % NPIX;
            const int iy  = rem / WG, jx = rem % WG;
            const int y = 2 * iy + dy, x = 2 * jx + dx;
            float* orow = out + (size_t)((b * HIN + y) * WIN + x) * Cc
                              + ntile * 128 + nbase + r16;
            #pragma unroll
            for (int nf = 0; nf < 4; ++nf) orow[nf * 16] = acc[mf][nf][rr];
        }
    }
}

// ===========================================================================
// grad_wt fast (EXACT R8 version, confirmed 90 µs): A dbuf gload, B single
// reg-staged; 2 barriers/chunk; batch->XCD remap. 48KB LDS -> 3 blocks/CU.
// ===========================================================================
__global__ __launch_bounds__(256, 3) void k_grad_wt_f(
    const unsigned short* __restrict__ xt,
    const unsigned short* __restrict__ gpad,
    float* __restrict__ gw)
{
    __shared__ unsigned short At[2][128 * 64];
    __shared__ unsigned short Bt[128 * 64];

    const int t = threadIdx.x;
    const int l = t & 63, wave = t >> 6;
    const int mbase = (wave & 1) * 64, nbase = (wave >> 1) * 64;
    const int q = l >> 4, r16 = l & 15;

    const int L   = blockIdx.x;           // 0..1151
    const int xcd = L & 7, idx = L >> 3;
    const int b   = xcd + 8 * (idx / 36);
    const int tt  = idx % 36;
    const int tap = tt >> 2, tile = tt & 3;
    const int tci = (tile >> 1) * 128, tco = (tile & 1) * 128;
    const int ki = tap / 3, kj = tap % 3;
    const int par = (kj == 1);
    const int jsh = (kj == 2);

    const unsigned short* axp[4];
    #pragma unroll
    for (int u = 0; u < 4; ++u) {
        const int row = u * 32 + (t >> 3);
        const int gs  = (t & 7) ^ (row & 7) ^ ((row >> 4) & 7);
        const int r0  = ki + 2 * (gs >> 2);
        axp[u] = xt + (size_t)((b * 57 + r0) * 256 + tci + row) * 64 + par * 32 + (gs & 3) * 8;
    }

    const int o   = t >> 5;
    const int rs  = o >> 2;
    const int mo  = (o & 3) * 8;
    const int co4 = (t & 31) * 4;

    uint2 br[8];
    auto load_breg = [&](int cc) {
        const int i = 2 * cc + rs;
        const int base_i = (b * 29 + i + 1) * 29;
        #pragma unroll
        for (int jj = 0; jj < 8; ++jj) {
            const int j = mo + jj - jsh;
            uint2 v; v.x = 0u; v.y = 0u;
            if (j <= 27) v = *(const uint2*)(gpad + (size_t)(base_i + j + 1) * 256 + tco + co4);
            br[jj] = v;
        }
    };

    f32x4 acc[4][4];
    #pragma unroll
    for (int a = 0; a < 4; ++a)
        #pragma unroll
        for (int c = 0; c < 4; ++c) acc[a][c] = (f32x4){0.f, 0.f, 0.f, 0.f};

    int aoff[2][4], boff[2][4];
    #pragma unroll
    for (int kk = 0; kk < 2; ++kk)
        #pragma unroll
        for (int mf = 0; mf < 4; ++mf) {
            aoff[kk][mf] = swz64(mbase + mf * 16 + r16, kk * 32 + q * 8);
            boff[kk][mf] = swz64(nbase + mf * 16 + r16, kk * 32 + q * 8);
        }

    #pragma unroll
    for (int u = 0; u < 4; ++u) { gload16(axp[u], &At[0][u * 2048 + t * 8]); axp[u] += 65536; }
    load_breg(0);

    #pragma unroll 1
    for (int cc = 0; cc < 14; ++cc) {
        const int p = cc & 1, n = cc + 1;
        full_wait_barrier();                 // At[p]+br resident; MFMA(cc-1) done
        if (n < 14) {
            #pragma unroll
            for (int u = 0; u < 4; ++u) { gload16(axp[u], &At[n & 1][u * 2048 + t * 8]); axp[u] += 65536; }
        }
        __builtin_amdgcn_sched_barrier(0);
        {
            const unsigned short* bs = (const unsigned short*)br;
            #pragma unroll
            for (int c = 0; c < 4; ++c) {
                bf16x8 wv;
                #pragma unroll
                for (int jj = 0; jj < 8; ++jj) wv[jj] = (short)bs[jj * 4 + c];
                const int row  = co4 + c;
                const int gpos = o ^ (row & 7) ^ ((row >> 4) & 7);
                *(bf16x8*)&Bt[row * 64 + gpos * 8] = wv;
            }
        }
        if (n < 14) load_breg(n);            // fly across MFMA(cc)
        __builtin_amdgcn_sched_barrier(0);
        lgkm_wait_barrier();                 // Bt visible

        #pragma unroll
        for (int kk = 0; kk < 2; ++kk) {
            bf16x8 af[4], bfr[4];
            #pragma unroll
            for (int mf = 0; mf < 4; ++mf) af[mf]  = *(const bf16x8*)&At[p][aoff[kk][mf]];
            #pragma unroll
            for (int nf = 0; nf < 4; ++nf) bfr[nf] = *(const bf16x8*)&Bt[boff[kk][nf]];
            #pragma unroll
            for (int mf = 0; mf < 4; ++mf)
                #pragma unroll
                for (int nf = 0; nf < 4; ++nf)
                    acc[mf][nf] = __builtin_amdgcn_mfma_f32_16x16x32_bf16(
                        af[mf], bfr[nf], acc[mf][nf], 0, 0, 0);
        }
    }

    #pragma unroll
    for (int mf = 0; mf < 4; ++mf) {
        #pragma unroll
        for (int rr = 0; rr < 4; ++rr) {
            const int cirow = tci + mbase + mf * 16 + q * 4 + rr;
            float* dst = gw + (size_t)(tap * Cc + cirow) * Cc + tco + nbase + r16;
            #pragma unroll
            for (int nf = 0; nf < 4; ++nf) atomicAdd(dst + nf * 16, acc[mf][nf][rr]);
        }
    }
}

// ===========================================================================
// grad_bias from g_pad, VECTORIZED (16B/lane bf16x8, unlike R9's 2B scalar):
// 421 blocks x 64 rows; thread = 8 rows x 8 channels; LDS [8][256] reduce ->
// ONE atomic per channel per block (421/address, proven-safe band).
// Zero pad rows contribute 0. Reads 27.5MB vs k_bias's 103MB.
// ===========================================================================
__global__ __launch_bounds__(256) void k_bias_gp(
    const unsigned short* __restrict__ gp, float* __restrict__ bias)
{
    __shared__ float R[8][256];
    const int t = threadIdx.x;
    const int c8   = (t & 31) * 8;
    const int rsub = t >> 5;            // 0..7
    const int row0 = blockIdx.x * 64 + rsub * 8;

    float bsum[8];
    #pragma unroll
    for (int c = 0; c < 8; ++c) bsum[c] = 0.f;

    #pragma unroll
    for (int k = 0; k < 8; ++k) {
        const int row = row0 + k;
        if (row < GP_ROWS) {
            bf16x8 v = *(const bf16x8*)&gp[(size_t)row * 256 + c8];
            #pragma unroll
            for (int c = 0; c < 8; ++c)
                bsum[c] += bf2f((unsigned short)v[c]);
        }
    }

    #pragma unroll
    for (int c = 0; c < 8; ++c) R[rsub][c8 + c] = bsum[c];
    __syncthreads();
    float s = 0.f;
    #pragma unroll
    for (int r = 0; r < 8; ++r) s += R[r][t];
    atomicAdd(bias + t, s);
}

// grad_bias fallback (reads f32 g): 392 blocks x 64 pixels.
__global__ __launch_bounds__(256) void k_bias(
    const float* __restrict__ g, float* __restrict__ bias)
{
    const int t = threadIdx.x;
    const float* base = g + (size_t)blockIdx.x * 64 * Cc;
    float acc = 0.f;
    #pragma unroll 8
    for (int p = 0; p < 64; ++p) acc += base[(size_t)p * Cc + t];
    atomicAdd(bias + t, acc);
}

// ===========================================================================
// fallback kernels (R4, proven) — used only when ws_size is insufficient
// ===========================================================================
__global__ __launch_bounds__(256) void k_grad_in_fb(
    const float* __restrict__ g, const float* __restrict__ wt, float* __restrict__ out)
{
    __shared__ unsigned short ga[128 * 32];
    __shared__ unsigned short wb[128 * 32];
    const int t = threadIdx.x;
    const int l = t & 63, wave = t >> 6;
    const int mbase = (wave & 1) * 64, nbase = (wave >> 1) * 64;
    const int q = l >> 4, r16 = l & 15;
    const int mtile = blockIdx.x, ntile = blockIdx.y, cls = blockIdx.z;
    const int dy = cls >> 1, dx = cls & 1;
    const int sp = t >> 1, sc = (t & 1) * 16;
    const int P_s = mtile * 128 + sp;
    const int b_s = P_s / NPIX;
    const int rem_s = P_s % NPIX;
    const int iy_s = rem_s / WG, jx_s = rem_s % WG;
    const int sci = ntile * 128 + sp;
    f32x4 acc[4][4];
    #pragma unroll
    for (int a = 0; a < 4; ++a)
        #pragma unroll
        for (int b = 0; b < 4; ++b) acc[a][b] = (f32x4){0.f,0.f,0.f,0.f};
    int aoff[4], boff[4];
    #pragma unroll
    for (int mf = 0; mf < 4; ++mf) aoff[mf] = swz(mbase + mf * 16 + r16, q * 8);
    #pragma unroll
    for (int nf = 0; nf < 4; ++nf) boff[nf] = swz(nbase + nf * 16 + r16, q * 8);
    const int nky = dy ? 1 : 2, nkx = dx ? 1 : 2;
    for (int ty = 0; ty < nky; ++ty) {
        const int di = dy ? 0 : (ty == 0 ? -1 : 0);
        const int krow = dy ? 1 : (ty == 0 ? 2 : 0);
        for (int tx = 0; tx < nkx; ++tx) {
            const int dj = dx ? 0 : (tx == 0 ? -1 : 0);
            const int kcol = dx ? 1 : (tx == 0 ? 2 : 0);
            const int gi = iy_s + di, gj = jx_s + dj;
            const bool valid = (gi >= 0) && (gj >= 0);
            const float* __restrict__ gsrc = g + (size_t)((b_s * HG + gi) * WG + gj) * Cc + sc;
            const float* __restrict__ wsrc = wt + (size_t)((krow * 3 + kcol) * Cc + sci) * Cc + sc;
            float4 av[4], bv[4];
            #pragma unroll
            for (int u = 0; u < 4; ++u) {
                av[u] = make_float4(0.f,0.f,0.f,0.f);
                if (valid) av[u] = *(const float4*)(gsrc + u * 4);
                bv[u] = *(const float4*)(wsrc + u * 4);
            }
            #pragma unroll 1
            for (int co0 = 0; co0 < Cc; co0 += 32) {
                ushort4 ua[4], ub[4];
                #pragma unroll
                for (int u = 0; u < 4; ++u) {
                    ua[u] = (ushort4){f2bf(av[u].x), f2bf(av[u].y), f2bf(av[u].z), f2bf(av[u].w)};
                    ub[u] = (ushort4){f2bf(bv[u].x), f2bf(bv[u].y), f2bf(bv[u].z), f2bf(bv[u].w)};
                }
                if (co0 + 32 < Cc) {
                    #pragma unroll
                    for (int u = 0; u < 4; ++u) {
                        float4 a2 = make_float4(0.f,0.f,0.f,0.f);
                        if (valid) a2 = *(const float4*)(gsrc + co0 + 32 + u * 4);
                        float4 b2 = *(const float4*)(wsrc + co0 + 32 + u * 4);
                        av[u] = a2; bv[u] = b2;
                    }
                }
                lds_barrier();
                #pragma unroll
                for (int u = 0; u < 4; ++u) {
                    *(ushort4*)&ga[swz(sp, sc + u * 4)] = ua[u];
                    *(ushort4*)&wb[swz(sp, sc + u * 4)] = ub[u];
                }
                lds_barrier();
                bf16x8 af[4], bf[4];
                #pragma unroll
                for (int mf = 0; mf < 4; ++mf) af[mf] = *(const bf16x8*)&ga[aoff[mf]];
                #pragma unroll
                for (int nf = 0; nf < 4; ++nf) bf[nf] = *(const bf16x8*)&wb[boff[nf]];
                #pragma unroll
                for (int mf = 0; mf < 4; ++mf)
                    #pragma unroll
                    for (int nf = 0; nf < 4; ++nf)
                        acc[mf][nf] = __builtin_amdgcn_mfma_f32_16x16x32_bf16(
                            af[mf], bf[nf], acc[mf][nf], 0, 0, 0);
            }
        }
    }
    #pragma unroll
    for (int mf = 0; mf < 4; ++mf)
        #pragma unroll
        for (int rr = 0; rr < 4; ++rr) {
            const int P = mtile * 128 + mbase + mf * 16 + q * 4 + rr;
            const int b = P / NPIX;
            const int rem = P % NPIX;
            const int iy = rem / WG, jx = rem % WG;
            const int y = 2 * iy + dy, x = 2 * jx + dx;
            float* orow = out + (size_t)((b * HIN + y) * WIN + x) * Cc + ntile * 128 + nbase + r16;
            #pragma unroll
            for (int nf = 0; nf < 4; ++nf) orow[nf * 16] = acc[mf][nf][rr];
        }
}

__global__ __launch_bounds__(256) void k_grad_wt_fb(
    const float* __restrict__ g, const float* __restrict__ inp, float* __restrict__ gw)
{
    __shared__ unsigned short xa[128 * 64];
    __shared__ unsigned short xg[128 * 64];
    const int t = threadIdx.x;
    const int l = t & 63, wave = t >> 6;
    const int mbase = (wave & 1) * 64, nbase = (wave >> 1) * 64;
    const int q = l >> 4, r16 = l & 15;
    const int tci = (blockIdx.x >> 1) * 128, tco = (blockIdx.x & 1) * 128;
    const int tap = blockIdx.y;
    const int ki = tap / 3, kj = tap % 3;
    const int b = blockIdx.z;
    const int pg = t >> 5, p0 = pg * 8, c4 = (t & 31) * 4;
    f32x4 acc[4][4];
    #pragma unroll
    for (int a = 0; a < 4; ++a)
        #pragma unroll
        for (int c = 0; c < 4; ++c) acc[a][c] = (f32x4){0.f,0.f,0.f,0.f};
    int aoff[2][4], boff[2][4];
    #pragma unroll
    for (int kk = 0; kk < 2; ++kk)
        #pragma unroll
        for (int mf = 0; mf < 4; ++mf) {
            aoff[kk][mf] = swz64(mbase + mf * 16 + r16, kk * 32 + q * 8);
            boff[kk][mf] = swz64(nbase + mf * 16 + r16, kk * 32 + q * 8);
        }
    const float* __restrict__ gb = g + (size_t)b * NPIX * Cc;
    const float* __restrict__ ib = inp + (size_t)b * HIN * WIN * Cc;
    float4 xr[8], gr[8];
    auto load_chunk = [&](int cc) {
        #pragma unroll
        for (int j = 0; j < 8; ++j) {
            const int p = cc * 64 + p0 + j;
            const int i = p / WG, jw = p % WG;
            const int r = ki + 2 * i, s = kj + 2 * jw;
            const bool vx = (p < NPIX) && (r < HIN) && (s < WIN);
            const bool vg = (p < NPIX);
            float4 xv = make_float4(0.f,0.f,0.f,0.f), gv = xv;
            if (vx) xv = *(const float4*)(ib + (size_t)(r * WIN + s) * Cc + tci + c4);
            if (vg) gv = *(const float4*)(gb + (size_t)p * Cc + tco + c4);
            xr[j] = xv; gr[j] = gv;
        }
    };
    load_chunk(0);
    #pragma unroll 1
    for (int cc = 0; cc < 13; ++cc) {
        bf16x8 wx[4], wg[4];
        #pragma unroll
        for (int j = 0; j < 8; ++j) {
            wx[0][j] = (short)f2bf(xr[j].x); wx[1][j] = (short)f2bf(xr[j].y);
            wx[2][j] = (short)f2bf(xr[j].z); wx[3][j] = (short)f2bf(xr[j].w);
            wg[0][j] = (short)f2bf(gr[j].x); wg[1][j] = (short)f2bf(gr[j].y);
            wg[2][j] = (short)f2bf(gr[j].z); wg[3][j] = (short)f2bf(gr[j].w);
        }
        if (cc + 1 < 13) load_chunk(cc + 1);
        lds_barrier();
        #pragma unroll
        for (int c = 0; c < 4; ++c) {
            *(bf16x8*)&xa[swz64(c4 + c, p0)] = wx[c];
            *(bf16x8*)&xg[swz64(c4 + c, p0)] = wg[c];
        }
        lds_barrier();
        #pragma unroll
        for (int kk = 0; kk < 2; ++kk) {
            bf16x8 af[4], bfr[4];
            #pragma unroll
            for (int mf = 0; mf < 4; ++mf) af[mf] = *(const bf16x8*)&xa[aoff[kk][mf]];
            #pragma unroll
            for (int nf = 0; nf < 4; ++nf) bfr[nf] = *(const bf16x8*)&xg[boff[kk][nf]];
            #pragma unroll
            for (int mf = 0; mf < 4; ++mf)
                #pragma unroll
                for (int nf = 0; nf < 4; ++nf)
                    acc[mf][nf] = __builtin_amdgcn_mfma_f32_16x16x32_bf16(
                        af[mf], bfr[nf], acc[mf][nf], 0, 0, 0);
        }
    }
    #pragma unroll
    for (int mf = 0; mf < 4; ++mf)
        #pragma unroll
        for (int rr = 0; rr < 4; ++rr) {
            const int cirow = tci + mbase + mf * 16 + q * 4 + rr;
            float* dst = gw + (size_t)(tap * Cc + cirow) * Cc + tco + nbase + r16;
            #pragma unroll
            for (int nf = 0; nf < 4; ++nf) atomicAdd(dst + nf * 16, acc[mf][nf][rr]);
        }
}

extern "C" void kernel_launch(void* const* d_in, const int* in_sizes, int n_in,
                              void* d_out, int out_size, void* d_ws, size_t ws_size,
                              hipStream_t stream) {
    const float* g   = (const float*)d_in[0];   // grad_output [32,28,28,256]
    const float* inp = (const float*)d_in[1];   // inputs      [32,56,56,256]
    const float* wt  = (const float*)d_in[2];   // kernels     [3,3,256,256]
    float* out = (float*)d_out;

    const int nzero = GW_SIZE + 256;
    k_zero<<<(nzero + 255) / 256, 256, 0, stream>>>(out + GW_OFF, nzero);

    if (ws_size >= WS_NEED) {
        unsigned short* xt  = (unsigned short*)d_ws;
        unsigned short* gp  = xt + XT_E;
        unsigned short* wtb = gp + GPAD_E;
        k_prep_x   <<<dim3(57, 32), 256, 0, stream>>>(inp, xt);
        k_prep_gpad<<<dim3(29, 32), 256, 0, stream>>>(g, gp);
        k_prep_wt  <<<WTB_E / 2048, 256, 0, stream>>>(wt, wtb);
        k_grad_in_f<<<dim3(196, 2, 4), 256, 0, stream>>>(gp, wtb, out);
        k_grad_wt_f<<<1152, 256, 0, stream>>>(xt, gp, out + GW_OFF);
        k_bias_gp  <<<(GP_ROWS + 63) / 64, 256, 0, stream>>>(gp, out + BIAS_OFF);
    } else {
        k_grad_in_fb<<<dim3(196, 2, 4), 256, 0, stream>>>(g, wt, out);
        k_grad_wt_fb<<<dim3(4, 9, 32), 256, 0, stream>>>(g, inp, out + GW_OFF);
        k_bias<<<392, 256, 0, stream>>>(g, out + BIAS_OFF);
    }
}

// Round 15
// 193.645 us; speedup vs baseline: 1.0911x; 1.0646x over previous
//
#include <hip/hip_runtime.h>

#define Bn   32
#define HIN  56
#define WIN  56
#define Cc   256
#define HG   28
#define WG   28
#define NPIX (HG*WG)                    // 784

#define GIN_SIZE (Bn*HIN*WIN*Cc)        // 25690112
#define GW_SIZE  (9*Cc*Cc)              // 589824
#define GW_OFF   GIN_SIZE
#define BIAS_OFF (GW_OFF + GW_SIZE)

// workspace layout (bf16 elements)
#define XT_E   (32*57*256*64)           // X_t[b][r][ci][par][m32]
#define GPAD_E (32*29*29*256)           // g_pad[b][iy][jx][co]
#define WTB_E  (9*256*256)              // wt bf16 [tap][ci][co]
#define WS_NEED ((size_t)(XT_E + GPAD_E + WTB_E) * 2)
#define GP_ROWS (32*29*29)              // 26912

// fused-prep role boundaries
#define NB_PX   1824                    // prep_x: 57*32
#define NB_GP   928                     // prep_gpad: 29*32
#define NB_WT   288                     // prep_wt: WTB_E/2048
#define NZ_VEC  147520                  // (GW_SIZE+256)/4 float4s
#define NB_Z    577                     // ceil(147520/256)
#define NB_ALL  (NB_PX + NB_GP + NB_WT + NB_Z)   // 3617

typedef short bf16x8 __attribute__((ext_vector_type(8)));
typedef float f32x4  __attribute__((ext_vector_type(4)));

__device__ __forceinline__ unsigned short f2bf(float f) {
    return __builtin_bit_cast(unsigned short, (__bf16)f);
}
__device__ __forceinline__ float bf2f(unsigned short u) {
    union { unsigned int u; float f; } v; v.u = ((unsigned int)u) << 16;
    return v.f;
}

__device__ __forceinline__ void gload16(const void* g, void* lds) {
    __builtin_amdgcn_global_load_lds(
        (const __attribute__((address_space(1))) unsigned int*)g,
        (__attribute__((address_space(3))) unsigned int*)lds, 16, 0, 0);
}

// hard fence: all vmem+lds retired, then block barrier (rule #18 SGB after)
__device__ __forceinline__ void full_wait_barrier() {
    asm volatile("s_waitcnt vmcnt(0) lgkmcnt(0)" ::: "memory");
    __builtin_amdgcn_s_barrier();
    __builtin_amdgcn_sched_barrier(0);
}
__device__ __forceinline__ void lgkm_wait_barrier() {
    asm volatile("s_waitcnt lgkmcnt(0)" ::: "memory");
    __builtin_amdgcn_s_barrier();
    __builtin_amdgcn_sched_barrier(0);
}
__device__ __forceinline__ void lds_barrier() {   // fallback kernels
    asm volatile("s_waitcnt lgkmcnt(0)" ::: "memory");
    __builtin_amdgcn_s_barrier();
    asm volatile("" ::: "memory");
}

// [row][32] bf16 tile swizzle (fallback grad_in)
__device__ __forceinline__ int swz(int row, int k) {
    int g2 = (k >> 3) ^ (row & 3) ^ ((row >> 2) & 3);
    return row * 32 + (g2 << 3) + (k & 7);
}
// [row][64] bf16 tile swizzle (all 64-wide tiles)
__device__ __forceinline__ int swz64(int row, int k) {
    int gq = ((k >> 3) ^ (row & 7) ^ ((row >> 4) & 7)) & 7;
    return row * 64 + (gq << 3) + (k & 7);
}

__global__ __launch_bounds__(256) void k_zero(float* __restrict__ p, int n) {
    int i = blockIdx.x * 256 + threadIdx.x;
    if (i < n) p[i] = 0.f;
}

// ===========================================================================
// FUSED prep: one dispatch does {prep_x | prep_gpad | prep_wt | zero} by
// blockIdx role decode. All roles are mutually independent (disjoint
// outputs), bodies identical to the proven R5/R8 kernels. Removes 3
// stream-serialization gaps + the scalar 2305-block memset.
// ===========================================================================
__global__ __launch_bounds__(256) void k_prep_all(
    const float* __restrict__ g,        // [32,28,28,256]
    const float* __restrict__ X,        // [32,56,56,256]
    const float* __restrict__ w,        // [3,3,256,256]
    unsigned short* __restrict__ xt,
    unsigned short* __restrict__ gp,
    unsigned short* __restrict__ wb,
    float* __restrict__ zdst)           // gw..bias region (GW_SIZE+256 f32)
{
    __shared__ unsigned short L[256 * 64];
    const int bid = blockIdx.x;
    const int t   = threadIdx.x;

    if (bid < NB_PX) {
        // ---- prep_x (proven R5 body): r = bid%57, b = bid/57 ----
        const int r = bid % 57;
        const int b = bid / 57;
        unsigned short* __restrict__ orow = xt + (size_t)((b * 57 + r) * 256) * 64;

        if (r == 56) {
            bf16x8 z = (bf16x8){0,0,0,0,0,0,0,0};
            #pragma unroll
            for (int k = 0; k < 8; ++k)
                *(bf16x8*)&orow[(size_t)(t + 256 * k) * 8] = z;
            return;
        }
        const float* __restrict__ xr = X + (size_t)((b * 56 + r) * 56) * 256;

        #pragma unroll
        for (int a = 0; a < 2; ++a) {
            const int idx = t + 256 * a;
            const int o  = idx >> 6;
            const int ci = (idx & 63) * 4;
            ushort4 ev[4], od[4];
            if (o < 7) {
                float4 xv[8];
                #pragma unroll
                for (int jj = 0; jj < 8; ++jj)
                    xv[jj] = *(const float4*)(xr + (size_t)(8 * o + jj) * 256 + ci);
                #pragma unroll
                for (int c = 0; c < 4; ++c) {
                    ev[c] = (ushort4){f2bf(((const float*)&xv[0])[c]), f2bf(((const float*)&xv[2])[c]),
                                      f2bf(((const float*)&xv[4])[c]), f2bf(((const float*)&xv[6])[c])};
                    od[c] = (ushort4){f2bf(((const float*)&xv[1])[c]), f2bf(((const float*)&xv[3])[c]),
                                      f2bf(((const float*)&xv[5])[c]), f2bf(((const float*)&xv[7])[c])};
                }
            } else {
                #pragma unroll
                for (int c = 0; c < 4; ++c) { ev[c] = (ushort4){0,0,0,0}; od[c] = (ushort4){0,0,0,0}; }
            }
            #pragma unroll
            for (int c = 0; c < 4; ++c) {
                const int row = ci + c;
                const int rb  = (row & 7) ^ ((row >> 4) & 7);
                const int g0  = (o >> 1) ^ rb;
                const int g1  = (4 + (o >> 1)) ^ rb;
                *(ushort4*)&L[row * 64 + g0 * 8 + (o & 1) * 4] = ev[c];
                *(ushort4*)&L[row * 64 + g1 * 8 + (o & 1) * 4] = od[c];
            }
        }
        __syncthreads();
        const int rb = (t & 7) ^ ((t >> 4) & 7);
        #pragma unroll
        for (int G = 0; G < 8; ++G) {
            bf16x8 v = *(bf16x8*)&L[t * 64 + ((G ^ rb)) * 8];
            *(bf16x8*)&orow[t * 64 + G * 8] = v;
        }
    } else if (bid < NB_PX + NB_GP) {
        // ---- prep_gpad (proven R5 body): iy = rem%29, b = rem/29 ----
        const int rem = bid - NB_PX;
        const int iy = rem % 29;
        const int b  = rem / 29;
        const int co8 = (t & 31) * 8;
        for (int jx = (t >> 5); jx < 29; jx += 8) {
            bf16x8 v = (bf16x8){0,0,0,0,0,0,0,0};
            if (iy > 0 && jx > 0) {
                const float* src = g + (size_t)(((b * 28 + iy - 1) * 28) + jx - 1) * 256 + co8;
                float4 a0 = *(const float4*)(src);
                float4 a1 = *(const float4*)(src + 4);
                v = (bf16x8){(short)f2bf(a0.x),(short)f2bf(a0.y),(short)f2bf(a0.z),(short)f2bf(a0.w),
                             (short)f2bf(a1.x),(short)f2bf(a1.y),(short)f2bf(a1.z),(short)f2bf(a1.w)};
            }
            *(bf16x8*)&gp[(size_t)(((b * 29 + iy) * 29) + jx) * 256 + co8] = v;
        }
    } else if (bid < NB_PX + NB_GP + NB_WT) {
        // ---- prep_wt ----
        const int b2 = bid - NB_PX - NB_GP;
        const size_t i8 = (size_t)(b2 * 256 + t) * 8;
        float4 a0 = *(const float4*)(w + i8);
        float4 a1 = *(const float4*)(w + i8 + 4);
        bf16x8 v = (bf16x8){(short)f2bf(a0.x),(short)f2bf(a0.y),(short)f2bf(a0.z),(short)f2bf(a0.w),
                            (short)f2bf(a1.x),(short)f2bf(a1.y),(short)f2bf(a1.z),(short)f2bf(a1.w)};
        *(bf16x8*)&wb[i8] = v;
    } else {
        // ---- zero gw+bias (vectorized float4) ----
        const int i4 = (bid - NB_PX - NB_GP - NB_WT) * 256 + t;
        if (i4 < NZ_VEC)
            *(float4*)(zdst + (size_t)i4 * 4) = make_float4(0.f, 0.f, 0.f, 0.f);
    }
}

// ===========================================================================
// grad_in fast (EXACT R8 version, proven ~53 µs): grid (196,2,4),
// At[2]+Bt[2] gload-dbuf, 1 barrier/chunk, 64KB LDS -> 2 blocks/CU.
// ===========================================================================
__global__ __launch_bounds__(256, 2) void k_grad_in_f(
    const unsigned short* __restrict__ gpad,
    const unsigned short* __restrict__ wtb,
    float* __restrict__ out)
{
    __shared__ unsigned short At[2][128 * 64];
    __shared__ unsigned short Bt[2][128 * 64];

    const int t = threadIdx.x;
    const int l = t & 63, wave = t >> 6;
    const int mbase = (wave & 1) * 64, nbase = (wave >> 1) * 64;
    const int q = l >> 4, r16 = l & 15;
    const int mtile = blockIdx.x, ntile = blockIdx.y, cls = blockIdx.z;
    const int dy = cls >> 1, dx = cls & 1;
    const int nky = dy ? 1 : 2, nkx = dx ? 1 : 2;
    const bool nkx2 = (nkx == 2);
    const int NC = nky * nkx * 4;

    int gsv[4], ab[4], aiy[4], ajx[4];
    #pragma unroll
    for (int u = 0; u < 4; ++u) {
        const int row = u * 32 + (t >> 3);
        gsv[u] = (t & 7) ^ (row & 7) ^ ((row >> 4) & 7);
        const int P = mtile * 128 + row;
        ab[u] = P / NPIX;
        const int rem = P % NPIX;
        aiy[u] = rem / WG; ajx[u] = rem % WG;
    }

    f32x4 acc[4][4];
    #pragma unroll
    for (int a = 0; a < 4; ++a)
        #pragma unroll
        for (int b = 0; b < 4; ++b) acc[a][b] = (f32x4){0.f, 0.f, 0.f, 0.f};

    int aoff[2][4], boff[2][4];
    #pragma unroll
    for (int kk = 0; kk < 2; ++kk)
        #pragma unroll
        for (int mf = 0; mf < 4; ++mf) {
            aoff[kk][mf] = swz64(mbase + mf * 16 + r16, kk * 32 + q * 8);
            boff[kk][mf] = swz64(nbase + mf * 16 + r16, kk * 32 + q * 8);
        }

    auto prefetch = [&](int c, int buf) {
        const int tapi = c >> 2, co0 = (c & 3) << 6;
        const int ty = nkx2 ? (tapi >> 1) : tapi;
        const int tx = nkx2 ? (tapi & 1) : 0;
        const int di = dy ? 0 : (ty ? 0 : -1);
        const int dj = dx ? 0 : (tx ? 0 : -1);
        const int krow = dy ? 1 : (ty ? 0 : 2);
        const int kcol = dx ? 1 : (tx ? 0 : 2);
        const unsigned short* wb2 = wtb + (size_t)((krow * 3 + kcol) * 256 + ntile * 128) * 256 + co0;
        #pragma unroll
        for (int u = 0; u < 4; ++u) {
            const unsigned short* as2 = gpad
                + (size_t)(((ab[u] * 29 + aiy[u] + di + 1) * 29) + ajx[u] + dj + 1) * 256
                + 8 * gsv[u] + co0;
            gload16(as2, &At[buf][u * 2048 + t * 8]);
            gload16(wb2 + (size_t)(u * 32 + (t >> 3)) * 256 + 8 * gsv[u], &Bt[buf][u * 2048 + t * 8]);
        }
    };

    prefetch(0, 0);

    #pragma unroll 1
    for (int cc = 0; cc < NC; ++cc) {
        const int p = cc & 1, n = cc + 1;
        full_wait_barrier();                 // chunk cc resident; MFMA(cc-1) done everywhere
        if (n < NC) prefetch(n, n & 1);      // fly across MFMA(cc)
        __builtin_amdgcn_sched_barrier(0);

        #pragma unroll
        for (int kk = 0; kk < 2; ++kk) {
            bf16x8 af[4], bf[4];
            #pragma unroll
            for (int mf = 0; mf < 4; ++mf) af[mf] = *(const bf16x8*)&At[p][aoff[kk][mf]];
            #pragma unroll
            for (int nf = 0; nf < 4; ++nf) bf[nf] = *(const bf16x8*)&Bt[p][boff[kk][nf]];
            #pragma unroll
            for (int mf = 0; mf < 4; ++mf)
                #pragma unroll
                for (int nf = 0; nf < 4; ++nf)
                    acc[mf][nf] = __builtin_amdgcn_mfma_f32_16x16x32_bf16(
                        af[mf], bf[nf], acc[mf][nf], 0, 0, 0);
        }
    }

    #pragma unroll
    for (int mf = 0; mf < 4; ++mf) {
        #pragma unroll
        for (int rr = 0; rr < 4; ++rr) {
            const int P   = mtile * 128 + mbase + mf * 16 + q * 4 + rr;
            const int b   = P / NPIX;
            const int rem = P % NPIX;
            const int iy  = rem / WG, jx = rem % WG;
            const int y = 2 * iy + dy, x = 2 * jx + dx;
            float* orow = out + (size_t)((b * HIN + y) * WIN + x) * Cc
                              + ntile * 128 + nbase + r16;
            #pragma unroll
            for (int nf = 0; nf < 4; ++nf) orow[nf * 16] = acc[mf][nf][rr];
        }
    }
}

// ===========================================================================
// grad_wt fast (EXACT R8 version, confirmed 90 µs): A dbuf gload, B single
// reg-staged; 2 barriers/chunk; batch->XCD remap. 48KB LDS -> 3 blocks/CU.
// ===========================================================================
__global__ __launch_bounds__(256, 3) void k_grad_wt_f(
    const unsigned short* __restrict__ xt,
    const unsigned short* __restrict__ gpad,
    float* __restrict__ gw)
{
    __shared__ unsigned short At[2][128 * 64];
    __shared__ unsigned short Bt[128 * 64];

    const int t = threadIdx.x;
    const int l = t & 63, wave = t >> 6;
    const int mbase = (wave & 1) * 64, nbase = (wave >> 1) * 64;
    const int q = l >> 4, r16 = l & 15;

    const int L   = blockIdx.x;           // 0..1151
    const int xcd = L & 7, idx = L >> 3;
    const int b   = xcd + 8 * (idx / 36);
    const int tt  = idx % 36;
    const int tap = tt >> 2, tile = tt & 3;
    const int tci = (tile >> 1) * 128, tco = (tile & 1) * 128;
    const int ki = tap / 3, kj = tap % 3;
    const int par = (kj == 1);
    const int jsh = (kj == 2);

    const unsigned short* axp[4];
    #pragma unroll
    for (int u = 0; u < 4; ++u) {
        const int row = u * 32 + (t >> 3);
        const int gs  = (t & 7) ^ (row & 7) ^ ((row >> 4) & 7);
        const int r0  = ki + 2 * (gs >> 2);
        axp[u] = xt + (size_t)((b * 57 + r0) * 256 + tci + row) * 64 + par * 32 + (gs & 3) * 8;
    }

    const int o   = t >> 5;
    const int rs  = o >> 2;
    const int mo  = (o & 3) * 8;
    const int co4 = (t & 31) * 4;

    uint2 br[8];
    auto load_breg = [&](int cc) {
        const int i = 2 * cc + rs;
        const int base_i = (b * 29 + i + 1) * 29;
        #pragma unroll
        for (int jj = 0; jj < 8; ++jj) {
            const int j = mo + jj - jsh;
            uint2 v; v.x = 0u; v.y = 0u;
            if (j <= 27) v = *(const uint2*)(gpad + (size_t)(base_i + j + 1) * 256 + tco + co4);
            br[jj] = v;
        }
    };

    f32x4 acc[4][4];
    #pragma unroll
    for (int a = 0; a < 4; ++a)
        #pragma unroll
        for (int c = 0; c < 4; ++c) acc[a][c] = (f32x4){0.f, 0.f, 0.f, 0.f};

    int aoff[2][4], boff[2][4];
    #pragma unroll
    for (int kk = 0; kk < 2; ++kk)
        #pragma unroll
        for (int mf = 0; mf < 4; ++mf) {
            aoff[kk][mf] = swz64(mbase + mf * 16 + r16, kk * 32 + q * 8);
            boff[kk][mf] = swz64(nbase + mf * 16 + r16, kk * 32 + q * 8);
        }

    #pragma unroll
    for (int u = 0; u < 4; ++u) { gload16(axp[u], &At[0][u * 2048 + t * 8]); axp[u] += 65536; }
    load_breg(0);

    #pragma unroll 1
    for (int cc = 0; cc < 14; ++cc) {
        const int p = cc & 1, n = cc + 1;
        full_wait_barrier();                 // At[p]+br resident; MFMA(cc-1) done
        if (n < 14) {
            #pragma unroll
            for (int u = 0; u < 4; ++u) { gload16(axp[u], &At[n & 1][u * 2048 + t * 8]); axp[u] += 65536; }
        }
        __builtin_amdgcn_sched_barrier(0);
        {
            const unsigned short* bs = (const unsigned short*)br;
            #pragma unroll
            for (int c = 0; c < 4; ++c) {
                bf16x8 wv;
                #pragma unroll
                for (int jj = 0; jj < 8; ++jj) wv[jj] = (short)bs[jj * 4 + c];
                const int row  = co4 + c;
                const int gpos = o ^ (row & 7) ^ ((row >> 4) & 7);
                *(bf16x8*)&Bt[row * 64 + gpos * 8] = wv;
            }
        }
        if (n < 14) load_breg(n);            // fly across MFMA(cc)
        __builtin_amdgcn_sched_barrier(0);
        lgkm_wait_barrier();                 // Bt visible

        #pragma unroll
        for (int kk = 0; kk < 2; ++kk) {
            bf16x8 af[4], bfr[4];
            #pragma unroll
            for (int mf = 0; mf < 4; ++mf) af[mf]  = *(const bf16x8*)&At[p][aoff[kk][mf]];
            #pragma unroll
            for (int nf = 0; nf < 4; ++nf) bfr[nf] = *(const bf16x8*)&Bt[boff[kk][nf]];
            #pragma unroll
            for (int mf = 0; mf < 4; ++mf)
                #pragma unroll
                for (int nf = 0; nf < 4; ++nf)
                    acc[mf][nf] = __builtin_amdgcn_mfma_f32_16x16x32_bf16(
                        af[mf], bfr[nf], acc[mf][nf], 0, 0, 0);
        }
    }

    #pragma unroll
    for (int mf = 0; mf < 4; ++mf) {
        #pragma unroll
        for (int rr = 0; rr < 4; ++rr) {
            const int cirow = tci + mbase + mf * 16 + q * 4 + rr;
            float* dst = gw + (size_t)(tap * Cc + cirow) * Cc + tco + nbase + r16;
            #pragma unroll
            for (int nf = 0; nf < 4; ++nf) atomicAdd(dst + nf * 16, acc[mf][nf][rr]);
        }
    }
}

// ===========================================================================
// grad_bias from g_pad, vectorized (R14, kept): 421 blocks x 64 rows;
// LDS pre-reduce -> ONE atomic per channel per block.
// ===========================================================================
__global__ __launch_bounds__(256) void k_bias_gp(
    const unsigned short* __restrict__ gp, float* __restrict__ bias)
{
    __shared__ float R[8][256];
    const int t = threadIdx.x;
    const int c8   = (t & 31) * 8;
    const int rsub = t >> 5;            // 0..7
    const int row0 = blockIdx.x * 64 + rsub * 8;

    float bsum[8];
    #pragma unroll
    for (int c = 0; c < 8; ++c) bsum[c] = 0.f;

    #pragma unroll
    for (int k = 0; k < 8; ++k) {
        const int row = row0 + k;
        if (row < GP_ROWS) {
            bf16x8 v = *(const bf16x8*)&gp[(size_t)row * 256 + c8];
            #pragma unroll
            for (int c = 0; c < 8; ++c)
                bsum[c] += bf2f((unsigned short)v[c]);
        }
    }

    #pragma unroll
    for (int c = 0; c < 8; ++c) R[rsub][c8 + c] = bsum[c];
    __syncthreads();
    float s = 0.f;
    #pragma unroll
    for (int r = 0; r < 8; ++r) s += R[r][t];
    atomicAdd(bias + t, s);
}

// grad_bias fallback (reads f32 g): 392 blocks x 64 pixels.
__global__ __launch_bounds__(256) void k_bias(
    const float* __restrict__ g, float* __restrict__ bias)
{
    const int t = threadIdx.x;
    const float* base = g + (size_t)blockIdx.x * 64 * Cc;
    float acc = 0.f;
    #pragma unroll 8
    for (int p = 0; p < 64; ++p) acc += base[(size_t)p * Cc + t];
    atomicAdd(bias + t, acc);
}

// ===========================================================================
// fallback kernels (R4, proven) — used only when ws_size is insufficient
// ===========================================================================
__global__ __launch_bounds__(256) void k_grad_in_fb(
    const float* __restrict__ g, const float* __restrict__ wt, float* __restrict__ out)
{
    __shared__ unsigned short ga[128 * 32];
    __shared__ unsigned short wb[128 * 32];
    const int t = threadIdx.x;
    const int l = t & 63, wave = t >> 6;
    const int mbase = (wave & 1) * 64, nbase = (wave >> 1) * 64;
    const int q = l >> 4, r16 = l & 15;
    const int mtile = blockIdx.x, ntile = blockIdx.y, cls = blockIdx.z;
    const int dy = cls >> 1, dx = cls & 1;
    const int sp = t >> 1, sc = (t & 1) * 16;
    const int P_s = mtile * 128 + sp;
    const int b_s = P_s / NPIX;
    const int rem_s = P_s % NPIX;
    const int iy_s = rem_s / WG, jx_s = rem_s % WG;
    const int sci = ntile * 128 + sp;
    f32x4 acc[4][4];
    #pragma unroll
    for (int a = 0; a < 4; ++a)
        #pragma unroll
        for (int b = 0; b < 4; ++b) acc[a][b] = (f32x4){0.f,0.f,0.f,0.f};
    int aoff[4], boff[4];
    #pragma unroll
    for (int mf = 0; mf < 4; ++mf) aoff[mf] = swz(mbase + mf * 16 + r16, q * 8);
    #pragma unroll
    for (int nf = 0; nf < 4; ++nf) boff[nf] = swz(nbase + nf * 16 + r16, q * 8);
    const int nky = dy ? 1 : 2, nkx = dx ? 1 : 2;
    for (int ty = 0; ty < nky; ++ty) {
        const int di = dy ? 0 : (ty == 0 ? -1 : 0);
        const int krow = dy ? 1 : (ty == 0 ? 2 : 0);
        for (int tx = 0; tx < nkx; ++tx) {
            const int dj = dx ? 0 : (tx == 0 ? -1 : 0);
            const int kcol = dx ? 1 : (tx == 0 ? 2 : 0);
            const int gi = iy_s + di, gj = jx_s + dj;
            const bool valid = (gi >= 0) && (gj >= 0);
            const float* __restrict__ gsrc = g + (size_t)((b_s * HG + gi) * WG + gj) * Cc + sc;
            const float* __restrict__ wsrc = wt + (size_t)((krow * 3 + kcol) * Cc + sci) * Cc + sc;
            float4 av[4], bv[4];
            #pragma unroll
            for (int u = 0; u < 4; ++u) {
                av[u] = make_float4(0.f,0.f,0.f,0.f);
                if (valid) av[u] = *(const float4*)(gsrc + u * 4);
                bv[u] = *(const float4*)(wsrc + u * 4);
            }
            #pragma unroll 1
            for (int co0 = 0; co0 < Cc; co0 += 32) {
                ushort4 ua[4], ub[4];
                #pragma unroll
                for (int u = 0; u < 4; ++u) {
                    ua[u] = (ushort4){f2bf(av[u].x), f2bf(av[u].y), f2bf(av[u].z), f2bf(av[u].w)};
                    ub[u] = (ushort4){f2bf(bv[u].x), f2bf(bv[u].y), f2bf(bv[u].z), f2bf(bv[u].w)};
                }
                if (co0 + 32 < Cc) {
                    #pragma unroll
                    for (int u = 0; u < 4; ++u) {
                        float4 a2 = make_float4(0.f,0.f,0.f,0.f);
                        if (valid) a2 = *(const float4*)(gsrc + co0 + 32 + u * 4);
                        float4 b2 = *(const float4*)(wsrc + co0 + 32 + u * 4);
                        av[u] = a2; bv[u] = b2;
                    }
                }
                lds_barrier();
                #pragma unroll
                for (int u = 0; u < 4; ++u) {
                    *(ushort4*)&ga[swz(sp, sc + u * 4)] = ua[u];
                    *(ushort4*)&wb[swz(sp, sc + u * 4)] = ub[u];
                }
                lds_barrier();
                bf16x8 af[4], bf[4];
                #pragma unroll
                for (int mf = 0; mf < 4; ++mf) af[mf] = *(const bf16x8*)&ga[aoff[mf]];
                #pragma unroll
                for (int nf = 0; nf < 4; ++nf) bf[nf] = *(const bf16x8*)&wb[boff[nf]];
                #pragma unroll
                for (int mf = 0; mf < 4; ++mf)
                    #pragma unroll
                    for (int nf = 0; nf < 4; ++nf)
                        acc[mf][nf] = __builtin_amdgcn_mfma_f32_16x16x32_bf16(
                            af[mf], bf[nf], acc[mf][nf], 0, 0, 0);
            }
        }
    }
    #pragma unroll
    for (int mf = 0; mf < 4; ++mf)
        #pragma unroll
        for (int rr = 0; rr < 4; ++rr) {
            const int P = mtile * 128 + mbase + mf * 16 + q * 4 + rr;
            const int b = P / NPIX;
            const int rem = P % NPIX;
            const int iy = rem / WG, jx = rem % WG;
            const int y = 2 * iy + dy, x = 2 * jx + dx;
            float* orow = out + (size_t)((b * HIN + y) * WIN + x) * Cc + ntile * 128 + nbase + r16;
            #pragma unroll
            for (int nf = 0; nf < 4; ++nf) orow[nf * 16] = acc[mf][nf][rr];
        }
}

__global__ __launch_bounds__(256) void k_grad_wt_fb(
    const float* __restrict__ g, const float* __restrict__ inp, float* __restrict__ gw)
{
    __shared__ unsigned short xa[128 * 64];
    __shared__ unsigned short xg[128 * 64];
    const int t = threadIdx.x;
    const int l = t & 63, wave = t >> 6;
    const int mbase = (wave & 1) * 64, nbase = (wave >> 1) * 64;
    const int q = l >> 4, r16 = l & 15;
    const int tci = (blockIdx.x >> 1) * 128, tco = (blockIdx.x & 1) * 128;
    const int tap = blockIdx.y;
    const int ki = tap / 3, kj = tap % 3;
    const int b = blockIdx.z;
    const int pg = t >> 5, p0 = pg * 8, c4 = (t & 31) * 4;
    f32x4 acc[4][4];
    #pragma unroll
    for (int a = 0; a < 4; ++a)
        #pragma unroll
        for (int c = 0; c < 4; ++c) acc[a][c] = (f32x4){0.f,0.f,0.f,0.f};
    int aoff[2][4], boff[2][4];
    #pragma unroll
    for (int kk = 0; kk < 2; ++kk)
        #pragma unroll
        for (int mf = 0; mf < 4; ++mf) {
            aoff[kk][mf] = swz64(mbase + mf * 16 + r16, kk * 32 + q * 8);
            boff[kk][mf] = swz64(nbase + mf * 16 + r16, kk * 32 + q * 8);
        }
    const float* __restrict__ gb = g + (size_t)b * NPIX * Cc;
    const float* __restrict__ ib = inp + (size_t)b * HIN * WIN * Cc;
    float4 xr[8], gr[8];
    auto load_chunk = [&](int cc) {
        #pragma unroll
        for (int j = 0; j < 8; ++j) {
            const int p = cc * 64 + p0 + j;
            const int i = p / WG, jw = p % WG;
            const int r = ki + 2 * i, s = kj + 2 * jw;
            const bool vx = (p < NPIX) && (r < HIN) && (s < WIN);
            const bool vg = (p < NPIX);
            float4 xv = make_float4(0.f,0.f,0.f,0.f), gv = xv;
            if (vx) xv = *(const float4*)(ib + (size_t)(r * WIN + s) * Cc + tci + c4);
            if (vg) gv = *(const float4*)(gb + (size_t)p * Cc + tco + c4);
            xr[j] = xv; gr[j] = gv;
        }
    };
    load_chunk(0);
    #pragma unroll 1
    for (int cc = 0; cc < 13; ++cc) {
        bf16x8 wx[4], wg[4];
        #pragma unroll
        for (int j = 0; j < 8; ++j) {
            wx[0][j] = (short)f2bf(xr[j].x); wx[1][j] = (short)f2bf(xr[j].y);
            wx[2][j] = (short)f2bf(xr[j].z); wx[3][j] = (short)f2bf(xr[j].w);
            wg[0][j] = (short)f2bf(gr[j].x); wg[1][j] = (short)f2bf(gr[j].y);
            wg[2][j] = (short)f2bf(gr[j].z); wg[3][j] = (short)f2bf(gr[j].w);
        }
        if (cc + 1 < 13) load_chunk(cc + 1);
        lds_barrier();
        #pragma unroll
        for (int c = 0; c < 4; ++c) {
            *(bf16x8*)&xa[swz64(c4 + c, p0)] = wx[c];
            *(bf16x8*)&xg[swz64(c4 + c, p0)] = wg[c];
        }
        lds_barrier();
        #pragma unroll
        for (int kk = 0; kk < 2; ++kk) {
            bf16x8 af[4], bfr[4];
            #pragma unroll
            for (int mf = 0; mf < 4; ++mf) af[mf] = *(const bf16x8*)&xa[aoff[kk][mf]];
            #pragma unroll
            for (int nf = 0; nf < 4; ++nf) bfr[nf] = *(const bf16x8*)&xg[boff[kk][nf]];
            #pragma unroll
            for (int mf = 0; mf < 4; ++mf)
                #pragma unroll
                for (int nf = 0; nf < 4; ++nf)
                    acc[mf][nf] = __builtin_amdgcn_mfma_f32_16x16x32_bf16(
                        af[mf], bfr[nf], acc[mf][nf], 0, 0, 0);
        }
    }
    #pragma unroll
    for (int mf = 0; mf < 4; ++mf)
        #pragma unroll
        for (int rr = 0; rr < 4; ++rr) {
            const int cirow = tci + mbase + mf * 16 + q * 4 + rr;
            float* dst = gw + (size_t)(tap * Cc + cirow) * Cc + tco + nbase + r16;
            #pragma unroll
            for (int nf = 0; nf < 4; ++nf) atomicAdd(dst + nf * 16, acc[mf][nf][rr]);
        }
}

extern "C" void kernel_launch(void* const* d_in, const int* in_sizes, int n_in,
                              void* d_out, int out_size, void* d_ws, size_t ws_size,
                              hipStream_t stream) {
    const float* g   = (const float*)d_in[0];   // grad_output [32,28,28,256]
    const float* inp = (const float*)d_in[1];   // inputs      [32,56,56,256]
    const float* wt  = (const float*)d_in[2];   // kernels     [3,3,256,256]
    float* out = (float*)d_out;

    if (ws_size >= WS_NEED) {
        unsigned short* xt  = (unsigned short*)d_ws;
        unsigned short* gp  = xt + XT_E;
        unsigned short* wtb = gp + GPAD_E;
        k_prep_all <<<NB_ALL, 256, 0, stream>>>(g, inp, wt, xt, gp, wtb, out + GW_OFF);
        k_grad_in_f<<<dim3(196, 2, 4), 256, 0, stream>>>(gp, wtb, out);
        k_grad_wt_f<<<1152, 256, 0, stream>>>(xt, gp, out + GW_OFF);
        k_bias_gp  <<<(GP_ROWS + 63) / 64, 256, 0, stream>>>(gp, out + BIAS_OFF);
    } else {
        const int nzero = GW_SIZE + 256;
        k_zero<<<(nzero + 255) / 256, 256, 0, stream>>>(out + GW_OFF, nzero);
        k_grad_in_fb<<<dim3(196, 2, 4), 256, 0, stream>>>(g, wt, out);
        k_grad_wt_fb<<<dim3(4, 9, 32), 256, 0, stream>>>(g, inp, out + GW_OFF);
        k_bias<<<392, 256, 0, stream>>>(g, out + BIAS_OFF);
    }
}

// Round 16
// 181.495 us; speedup vs baseline: 1.1641x; 1.0669x over previous
//
#include <hip/hip_runtime.h>

#define Bn   32
#define HIN  56
#define WIN  56
#define Cc   256
#define HG   28
#define WG   28
#define NPIX (HG*WG)                    // 784

#define GIN_SIZE (Bn*HIN*WIN*Cc)        // 25690112
#define GW_SIZE  (9*Cc*Cc)              // 589824
#define GW_OFF   GIN_SIZE
#define BIAS_OFF (GW_OFF + GW_SIZE)

// workspace layout (bf16 elements)
#define XT_E   (32*57*256*64)           // X_t[b][r][ci][par][m32]
#define GPAD_E (32*29*29*256)           // g_pad[b][iy][jx][co]
#define WTB_E  (9*256*256)              // wt bf16 [tap][ci][co]
#define WS_NEED ((size_t)(XT_E + GPAD_E + WTB_E) * 2)
#define GP_ROWS (32*29*29)              // 26912

// fused-prep role boundaries
#define NB_PX   1824                    // prep_x: 57*32
#define NB_GP   928                     // prep_gpad: 29*32
#define NB_WT   288                     // prep_wt: WTB_E/2048
#define NZ_VEC  147520                  // (GW_SIZE+256)/4 float4s
#define NB_Z    577                     // ceil(147520/256)
#define NB_ALL  (NB_PX + NB_GP + NB_WT + NB_Z)   // 3617

// grad_wt + bias fused grid
#define NB_GWT  1152
#define NB_BIAS 421                     // ceil(GP_ROWS/64)
#define NB_GWTB (NB_GWT + NB_BIAS)      // 1573

typedef short bf16x8 __attribute__((ext_vector_type(8)));
typedef float f32x4  __attribute__((ext_vector_type(4)));

__device__ __forceinline__ unsigned short f2bf(float f) {
    return __builtin_bit_cast(unsigned short, (__bf16)f);
}
__device__ __forceinline__ float bf2f(unsigned short u) {
    union { unsigned int u; float f; } v; v.u = ((unsigned int)u) << 16;
    return v.f;
}

__device__ __forceinline__ void gload16(const void* g, void* lds) {
    __builtin_amdgcn_global_load_lds(
        (const __attribute__((address_space(1))) unsigned int*)g,
        (__attribute__((address_space(3))) unsigned int*)lds, 16, 0, 0);
}

// hard fence: all vmem+lds retired, then block barrier (rule #18 SGB after)
__device__ __forceinline__ void full_wait_barrier() {
    asm volatile("s_waitcnt vmcnt(0) lgkmcnt(0)" ::: "memory");
    __builtin_amdgcn_s_barrier();
    __builtin_amdgcn_sched_barrier(0);
}
__device__ __forceinline__ void lgkm_wait_barrier() {
    asm volatile("s_waitcnt lgkmcnt(0)" ::: "memory");
    __builtin_amdgcn_s_barrier();
    __builtin_amdgcn_sched_barrier(0);
}
__device__ __forceinline__ void lds_barrier() {   // fallback kernels
    asm volatile("s_waitcnt lgkmcnt(0)" ::: "memory");
    __builtin_amdgcn_s_barrier();
    asm volatile("" ::: "memory");
}

// [row][32] bf16 tile swizzle (fallback grad_in)
__device__ __forceinline__ int swz(int row, int k) {
    int g2 = (k >> 3) ^ (row & 3) ^ ((row >> 2) & 3);
    return row * 32 + (g2 << 3) + (k & 7);
}
// [row][64] bf16 tile swizzle (all 64-wide tiles)
__device__ __forceinline__ int swz64(int row, int k) {
    int gq = ((k >> 3) ^ (row & 7) ^ ((row >> 4) & 7)) & 7;
    return row * 64 + (gq << 3) + (k & 7);
}

__global__ __launch_bounds__(256) void k_zero(float* __restrict__ p, int n) {
    int i = blockIdx.x * 256 + threadIdx.x;
    if (i < n) p[i] = 0.f;
}

// ===========================================================================
// FUSED prep (R15, proven): {prep_x | prep_gpad | prep_wt | zero} by
// blockIdx role decode. Roles independent, bodies = proven R5/R8 kernels.
// ===========================================================================
__global__ __launch_bounds__(256) void k_prep_all(
    const float* __restrict__ g,        // [32,28,28,256]
    const float* __restrict__ X,        // [32,56,56,256]
    const float* __restrict__ w,        // [3,3,256,256]
    unsigned short* __restrict__ xt,
    unsigned short* __restrict__ gp,
    unsigned short* __restrict__ wb,
    float* __restrict__ zdst)           // gw..bias region (GW_SIZE+256 f32)
{
    __shared__ unsigned short L[256 * 64];
    const int bid = blockIdx.x;
    const int t   = threadIdx.x;

    if (bid < NB_PX) {
        // ---- prep_x (proven R5 body): r = bid%57, b = bid/57 ----
        const int r = bid % 57;
        const int b = bid / 57;
        unsigned short* __restrict__ orow = xt + (size_t)((b * 57 + r) * 256) * 64;

        if (r == 56) {
            bf16x8 z = (bf16x8){0,0,0,0,0,0,0,0};
            #pragma unroll
            for (int k = 0; k < 8; ++k)
                *(bf16x8*)&orow[(size_t)(t + 256 * k) * 8] = z;
            return;
        }
        const float* __restrict__ xr = X + (size_t)((b * 56 + r) * 56) * 256;

        #pragma unroll
        for (int a = 0; a < 2; ++a) {
            const int idx = t + 256 * a;
            const int o  = idx >> 6;
            const int ci = (idx & 63) * 4;
            ushort4 ev[4], od[4];
            if (o < 7) {
                float4 xv[8];
                #pragma unroll
                for (int jj = 0; jj < 8; ++jj)
                    xv[jj] = *(const float4*)(xr + (size_t)(8 * o + jj) * 256 + ci);
                #pragma unroll
                for (int c = 0; c < 4; ++c) {
                    ev[c] = (ushort4){f2bf(((const float*)&xv[0])[c]), f2bf(((const float*)&xv[2])[c]),
                                      f2bf(((const float*)&xv[4])[c]), f2bf(((const float*)&xv[6])[c])};
                    od[c] = (ushort4){f2bf(((const float*)&xv[1])[c]), f2bf(((const float*)&xv[3])[c]),
                                      f2bf(((const float*)&xv[5])[c]), f2bf(((const float*)&xv[7])[c])};
                }
            } else {
                #pragma unroll
                for (int c = 0; c < 4; ++c) { ev[c] = (ushort4){0,0,0,0}; od[c] = (ushort4){0,0,0,0}; }
            }
            #pragma unroll
            for (int c = 0; c < 4; ++c) {
                const int row = ci + c;
                const int rb  = (row & 7) ^ ((row >> 4) & 7);
                const int g0  = (o >> 1) ^ rb;
                const int g1  = (4 + (o >> 1)) ^ rb;
                *(ushort4*)&L[row * 64 + g0 * 8 + (o & 1) * 4] = ev[c];
                *(ushort4*)&L[row * 64 + g1 * 8 + (o & 1) * 4] = od[c];
            }
        }
        __syncthreads();
        const int rb = (t & 7) ^ ((t >> 4) & 7);
        #pragma unroll
        for (int G = 0; G < 8; ++G) {
            bf16x8 v = *(bf16x8*)&L[t * 64 + ((G ^ rb)) * 8];
            *(bf16x8*)&orow[t * 64 + G * 8] = v;
        }
    } else if (bid < NB_PX + NB_GP) {
        // ---- prep_gpad (proven R5 body): iy = rem%29, b = rem/29 ----
        const int rem = bid - NB_PX;
        const int iy = rem % 29;
        const int b  = rem / 29;
        const int co8 = (t & 31) * 8;
        for (int jx = (t >> 5); jx < 29; jx += 8) {
            bf16x8 v = (bf16x8){0,0,0,0,0,0,0,0};
            if (iy > 0 && jx > 0) {
                const float* src = g + (size_t)(((b * 28 + iy - 1) * 28) + jx - 1) * 256 + co8;
                float4 a0 = *(const float4*)(src);
                float4 a1 = *(const float4*)(src + 4);
                v = (bf16x8){(short)f2bf(a0.x),(short)f2bf(a0.y),(short)f2bf(a0.z),(short)f2bf(a0.w),
                             (short)f2bf(a1.x),(short)f2bf(a1.y),(short)f2bf(a1.z),(short)f2bf(a1.w)};
            }
            *(bf16x8*)&gp[(size_t)(((b * 29 + iy) * 29) + jx) * 256 + co8] = v;
        }
    } else if (bid < NB_PX + NB_GP + NB_WT) {
        // ---- prep_wt ----
        const int b2 = bid - NB_PX - NB_GP;
        const size_t i8 = (size_t)(b2 * 256 + t) * 8;
        float4 a0 = *(const float4*)(w + i8);
        float4 a1 = *(const float4*)(w + i8 + 4);
        bf16x8 v = (bf16x8){(short)f2bf(a0.x),(short)f2bf(a0.y),(short)f2bf(a0.z),(short)f2bf(a0.w),
                            (short)f2bf(a1.x),(short)f2bf(a1.y),(short)f2bf(a1.z),(short)f2bf(a1.w)};
        *(bf16x8*)&wb[i8] = v;
    } else {
        // ---- zero gw+bias (vectorized float4) ----
        const int i4 = (bid - NB_PX - NB_GP - NB_WT) * 256 + t;
        if (i4 < NZ_VEC)
            *(float4*)(zdst + (size_t)i4 * 4) = make_float4(0.f, 0.f, 0.f, 0.f);
    }
}

// ===========================================================================
// grad_in fast (EXACT R8 version, proven ~53 µs): grid (196,2,4),
// At[2]+Bt[2] gload-dbuf, 1 barrier/chunk, 64KB LDS -> 2 blocks/CU.
// ===========================================================================
__global__ __launch_bounds__(256, 2) void k_grad_in_f(
    const unsigned short* __restrict__ gpad,
    const unsigned short* __restrict__ wtb,
    float* __restrict__ out)
{
    __shared__ unsigned short At[2][128 * 64];
    __shared__ unsigned short Bt[2][128 * 64];

    const int t = threadIdx.x;
    const int l = t & 63, wave = t >> 6;
    const int mbase = (wave & 1) * 64, nbase = (wave >> 1) * 64;
    const int q = l >> 4, r16 = l & 15;
    const int mtile = blockIdx.x, ntile = blockIdx.y, cls = blockIdx.z;
    const int dy = cls >> 1, dx = cls & 1;
    const int nky = dy ? 1 : 2, nkx = dx ? 1 : 2;
    const bool nkx2 = (nkx == 2);
    const int NC = nky * nkx * 4;

    int gsv[4], ab[4], aiy[4], ajx[4];
    #pragma unroll
    for (int u = 0; u < 4; ++u) {
        const int row = u * 32 + (t >> 3);
        gsv[u] = (t & 7) ^ (row & 7) ^ ((row >> 4) & 7);
        const int P = mtile * 128 + row;
        ab[u] = P / NPIX;
        const int rem = P % NPIX;
        aiy[u] = rem / WG; ajx[u] = rem % WG;
    }

    f32x4 acc[4][4];
    #pragma unroll
    for (int a = 0; a < 4; ++a)
        #pragma unroll
        for (int b = 0; b < 4; ++b) acc[a][b] = (f32x4){0.f, 0.f, 0.f, 0.f};

    int aoff[2][4], boff[2][4];
    #pragma unroll
    for (int kk = 0; kk < 2; ++kk)
        #pragma unroll
        for (int mf = 0; mf < 4; ++mf) {
            aoff[kk][mf] = swz64(mbase + mf * 16 + r16, kk * 32 + q * 8);
            boff[kk][mf] = swz64(nbase + mf * 16 + r16, kk * 32 + q * 8);
        }

    auto prefetch = [&](int c, int buf) {
        const int tapi = c >> 2, co0 = (c & 3) << 6;
        const int ty = nkx2 ? (tapi >> 1) : tapi;
        const int tx = nkx2 ? (tapi & 1) : 0;
        const int di = dy ? 0 : (ty ? 0 : -1);
        const int dj = dx ? 0 : (tx ? 0 : -1);
        const int krow = dy ? 1 : (ty ? 0 : 2);
        const int kcol = dx ? 1 : (tx ? 0 : 2);
        const unsigned short* wb2 = wtb + (size_t)((krow * 3 + kcol) * 256 + ntile * 128) * 256 + co0;
        #pragma unroll
        for (int u = 0; u < 4; ++u) {
            const unsigned short* as2 = gpad
                + (size_t)(((ab[u] * 29 + aiy[u] + di + 1) * 29) + ajx[u] + dj + 1) * 256
                + 8 * gsv[u] + co0;
            gload16(as2, &At[buf][u * 2048 + t * 8]);
            gload16(wb2 + (size_t)(u * 32 + (t >> 3)) * 256 + 8 * gsv[u], &Bt[buf][u * 2048 + t * 8]);
        }
    };

    prefetch(0, 0);

    #pragma unroll 1
    for (int cc = 0; cc < NC; ++cc) {
        const int p = cc & 1, n = cc + 1;
        full_wait_barrier();                 // chunk cc resident; MFMA(cc-1) done everywhere
        if (n < NC) prefetch(n, n & 1);      // fly across MFMA(cc)
        __builtin_amdgcn_sched_barrier(0);

        #pragma unroll
        for (int kk = 0; kk < 2; ++kk) {
            bf16x8 af[4], bf[4];
            #pragma unroll
            for (int mf = 0; mf < 4; ++mf) af[mf] = *(const bf16x8*)&At[p][aoff[kk][mf]];
            #pragma unroll
            for (int nf = 0; nf < 4; ++nf) bf[nf] = *(const bf16x8*)&Bt[p][boff[kk][nf]];
            #pragma unroll
            for (int mf = 0; mf < 4; ++mf)
                #pragma unroll
                for (int nf = 0; nf < 4; ++nf)
                    acc[mf][nf] = __builtin_amdgcn_mfma_f32_16x16x32_bf16(
                        af[mf], bf[nf], acc[mf][nf], 0, 0, 0);
        }
    }

    #pragma unroll
    for (int mf = 0; mf < 4; ++mf) {
        #pragma unroll
        for (int rr = 0; rr < 4; ++rr) {
            const int P   = mtile * 128 + mbase + mf * 16 + q * 4 + rr;
            const int b   = P / NPIX;
            const int rem = P % NPIX;
            const int iy  = rem / WG, jx = rem % WG;
            const int y = 2 * iy + dy, x = 2 * jx + dx;
            float* orow = out + (size_t)((b * HIN + y) * WIN + x) * Cc
                              + ntile * 128 + nbase + r16;
            #pragma unroll
            for (int nf = 0; nf < 4; ++nf) orow[nf * 16] = acc[mf][nf][rr];
        }
    }
}

// ===========================================================================
// grad_wt fast + fused bias tail: blocks 0..1151 = EXACT R8 grad_wt body
// (A dbuf gload, B reg-staged, 2 barriers/chunk, batch->XCD remap, 48KB);
// blocks 1152..1572 = bias role (proven R14 bias_gp body, LDS reused from
// At) — they fill the GEMM grid's idle tail (1152 blocks / 768 slots).
// ===========================================================================
__global__ __launch_bounds__(256, 3) void k_grad_wt_f(
    const unsigned short* __restrict__ xt,
    const unsigned short* __restrict__ gpad,
    float* __restrict__ gw,
    float* __restrict__ bias)
{
    __shared__ unsigned short At[2][128 * 64];
    __shared__ unsigned short Bt[128 * 64];

    const int bid = blockIdx.x;
    const int t = threadIdx.x;

    if (bid >= NB_GWT) {
        // ---- bias role (proven R14 body; one atomic/channel/block) ----
        float* R = (float*)&At[0][0];       // reuse 8KB of At
        const int c8   = (t & 31) * 8;
        const int rsub = t >> 5;            // 0..7
        const int row0 = (bid - NB_GWT) * 64 + rsub * 8;

        float bsum[8];
        #pragma unroll
        for (int c = 0; c < 8; ++c) bsum[c] = 0.f;

        #pragma unroll
        for (int k = 0; k < 8; ++k) {
            const int row = row0 + k;
            if (row < GP_ROWS) {
                bf16x8 v = *(const bf16x8*)&gpad[(size_t)row * 256 + c8];
                #pragma unroll
                for (int c = 0; c < 8; ++c)
                    bsum[c] += bf2f((unsigned short)v[c]);
            }
        }
        #pragma unroll
        for (int c = 0; c < 8; ++c) R[rsub * 256 + c8 + c] = bsum[c];
        __syncthreads();
        float s = 0.f;
        #pragma unroll
        for (int r = 0; r < 8; ++r) s += R[r * 256 + t];
        atomicAdd(bias + t, s);
        return;
    }

    const int l = t & 63, wave = t >> 6;
    const int mbase = (wave & 1) * 64, nbase = (wave >> 1) * 64;
    const int q = l >> 4, r16 = l & 15;

    const int L   = bid;                  // 0..1151
    const int xcd = L & 7, idx = L >> 3;
    const int b   = xcd + 8 * (idx / 36);
    const int tt  = idx % 36;
    const int tap = tt >> 2, tile = tt & 3;
    const int tci = (tile >> 1) * 128, tco = (tile & 1) * 128;
    const int ki = tap / 3, kj = tap % 3;
    const int par = (kj == 1);
    const int jsh = (kj == 2);

    const unsigned short* axp[4];
    #pragma unroll
    for (int u = 0; u < 4; ++u) {
        const int row = u * 32 + (t >> 3);
        const int gs  = (t & 7) ^ (row & 7) ^ ((row >> 4) & 7);
        const int r0  = ki + 2 * (gs >> 2);
        axp[u] = xt + (size_t)((b * 57 + r0) * 256 + tci + row) * 64 + par * 32 + (gs & 3) * 8;
    }

    const int o   = t >> 5;
    const int rs  = o >> 2;
    const int mo  = (o & 3) * 8;
    const int co4 = (t & 31) * 4;

    uint2 br[8];
    auto load_breg = [&](int cc) {
        const int i = 2 * cc + rs;
        const int base_i = (b * 29 + i + 1) * 29;
        #pragma unroll
        for (int jj = 0; jj < 8; ++jj) {
            const int j = mo + jj - jsh;
            uint2 v; v.x = 0u; v.y = 0u;
            if (j <= 27) v = *(const uint2*)(gpad + (size_t)(base_i + j + 1) * 256 + tco + co4);
            br[jj] = v;
        }
    };

    f32x4 acc[4][4];
    #pragma unroll
    for (int a = 0; a < 4; ++a)
        #pragma unroll
        for (int c = 0; c < 4; ++c) acc[a][c] = (f32x4){0.f, 0.f, 0.f, 0.f};

    int aoff[2][4], boff[2][4];
    #pragma unroll
    for (int kk = 0; kk < 2; ++kk)
        #pragma unroll
        for (int mf = 0; mf < 4; ++mf) {
            aoff[kk][mf] = swz64(mbase + mf * 16 + r16, kk * 32 + q * 8);
            boff[kk][mf] = swz64(nbase + mf * 16 + r16, kk * 32 + q * 8);
        }

    #pragma unroll
    for (int u = 0; u < 4; ++u) { gload16(axp[u], &At[0][u * 2048 + t * 8]); axp[u] += 65536; }
    load_breg(0);

    #pragma unroll 1
    for (int cc = 0; cc < 14; ++cc) {
        const int p = cc & 1, n = cc + 1;
        full_wait_barrier();                 // At[p]+br resident; MFMA(cc-1) done
        if (n < 14) {
            #pragma unroll
            for (int u = 0; u < 4; ++u) { gload16(axp[u], &At[n & 1][u * 2048 + t * 8]); axp[u] += 65536; }
        }
        __builtin_amdgcn_sched_barrier(0);
        {
            const unsigned short* bs = (const unsigned short*)br;
            #pragma unroll
            for (int c = 0; c < 4; ++c) {
                bf16x8 wv;
                #pragma unroll
                for (int jj = 0; jj < 8; ++jj) wv[jj] = (short)bs[jj * 4 + c];
                const int row  = co4 + c;
                const int gpos = o ^ (row & 7) ^ ((row >> 4) & 7);
                *(bf16x8*)&Bt[row * 64 + gpos * 8] = wv;
            }
        }
        if (n < 14) load_breg(n);            // fly across MFMA(cc)
        __builtin_amdgcn_sched_barrier(0);
        lgkm_wait_barrier();                 // Bt visible

        #pragma unroll
        for (int kk = 0; kk < 2; ++kk) {
            bf16x8 af[4], bfr[4];
            #pragma unroll
            for (int mf = 0; mf < 4; ++mf) af[mf]  = *(const bf16x8*)&At[p][aoff[kk][mf]];
            #pragma unroll
            for (int nf = 0; nf < 4; ++nf) bfr[nf] = *(const bf16x8*)&Bt[boff[kk][nf]];
            #pragma unroll
            for (int mf = 0; mf < 4; ++mf)
                #pragma unroll
                for (int nf = 0; nf < 4; ++nf)
                    acc[mf][nf] = __builtin_amdgcn_mfma_f32_16x16x32_bf16(
                        af[mf], bfr[nf], acc[mf][nf], 0, 0, 0);
        }
    }

    #pragma unroll
    for (int mf = 0; mf < 4; ++mf) {
        #pragma unroll
        for (int rr = 0; rr < 4; ++rr) {
            const int cirow = tci + mbase + mf * 16 + q * 4 + rr;
            float* dst = gw + (size_t)(tap * Cc + cirow) * Cc + tco + nbase + r16;
            #pragma unroll
            for (int nf = 0; nf < 4; ++nf) atomicAdd(dst + nf * 16, acc[mf][nf][rr]);
        }
    }
}

// grad_bias fallback (reads f32 g): 392 blocks x 64 pixels.
__global__ __launch_bounds__(256) void k_bias(
    const float* __restrict__ g, float* __restrict__ bias)
{
    const int t = threadIdx.x;
    const float* base = g + (size_t)blockIdx.x * 64 * Cc;
    float acc = 0.f;
    #pragma unroll 8
    for (int p = 0; p < 64; ++p) acc += base[(size_t)p * Cc + t];
    atomicAdd(bias + t, acc);
}

// ===========================================================================
// fallback kernels (R4, proven) — used only when ws_size is insufficient
// ===========================================================================
__global__ __launch_bounds__(256) void k_grad_in_fb(
    const float* __restrict__ g, const float* __restrict__ wt, float* __restrict__ out)
{
    __shared__ unsigned short ga[128 * 32];
    __shared__ unsigned short wb[128 * 32];
    const int t = threadIdx.x;
    const int l = t & 63, wave = t >> 6;
    const int mbase = (wave & 1) * 64, nbase = (wave >> 1) * 64;
    const int q = l >> 4, r16 = l & 15;
    const int mtile = blockIdx.x, ntile = blockIdx.y, cls = blockIdx.z;
    const int dy = cls >> 1, dx = cls & 1;
    const int sp = t >> 1, sc = (t & 1) * 16;
    const int P_s = mtile * 128 + sp;
    const int b_s = P_s / NPIX;
    const int rem_s = P_s % NPIX;
    const int iy_s = rem_s / WG, jx_s = rem_s % WG;
    const int sci = ntile * 128 + sp;
    f32x4 acc[4][4];
    #pragma unroll
    for (int a = 0; a < 4; ++a)
        #pragma unroll
        for (int b = 0; b < 4; ++b) acc[a][b] = (f32x4){0.f,0.f,0.f,0.f};
    int aoff[4], boff[4];
    #pragma unroll
    for (int mf = 0; mf < 4; ++mf) aoff[mf] = swz(mbase + mf * 16 + r16, q * 8);
    #pragma unroll
    for (int nf = 0; nf < 4; ++nf) boff[nf] = swz(nbase + nf * 16 + r16, q * 8);
    const int nky = dy ? 1 : 2, nkx = dx ? 1 : 2;
    for (int ty = 0; ty < nky; ++ty) {
        const int di = dy ? 0 : (ty == 0 ? -1 : 0);
        const int krow = dy ? 1 : (ty == 0 ? 2 : 0);
        for (int tx = 0; tx < nkx; ++tx) {
            const int dj = dx ? 0 : (tx == 0 ? -1 : 0);
            const int kcol = dx ? 1 : (tx == 0 ? 2 : 0);
            const int gi = iy_s + di, gj = jx_s + dj;
            const bool valid = (gi >= 0) && (gj >= 0);
            const float* __restrict__ gsrc = g + (size_t)((b_s * HG + gi) * WG + gj) * Cc + sc;
            const float* __restrict__ wsrc = wt + (size_t)((krow * 3 + kcol) * Cc + sci) * Cc + sc;
            float4 av[4], bv[4];
            #pragma unroll
            for (int u = 0; u < 4; ++u) {
                av[u] = make_float4(0.f,0.f,0.f,0.f);
                if (valid) av[u] = *(const float4*)(gsrc + u * 4);
                bv[u] = *(const float4*)(wsrc + u * 4);
            }
            #pragma unroll 1
            for (int co0 = 0; co0 < Cc; co0 += 32) {
                ushort4 ua[4], ub[4];
                #pragma unroll
                for (int u = 0; u < 4; ++u) {
                    ua[u] = (ushort4){f2bf(av[u].x), f2bf(av[u].y), f2bf(av[u].z), f2bf(av[u].w)};
                    ub[u] = (ushort4){f2bf(bv[u].x), f2bf(bv[u].y), f2bf(bv[u].z), f2bf(bv[u].w)};
                }
                if (co0 + 32 < Cc) {
                    #pragma unroll
                    for (int u = 0; u < 4; ++u) {
                        float4 a2 = make_float4(0.f,0.f,0.f,0.f);
                        if (valid) a2 = *(const float4*)(gsrc + co0 + 32 + u * 4);
                        float4 b2 = *(const float4*)(wsrc + co0 + 32 + u * 4);
                        av[u] = a2; bv[u] = b2;
                    }
                }
                lds_barrier();
                #pragma unroll
                for (int u = 0; u < 4; ++u) {
                    *(ushort4*)&ga[swz(sp, sc + u * 4)] = ua[u];
                    *(ushort4*)&wb[swz(sp, sc + u * 4)] = ub[u];
                }
                lds_barrier();
                bf16x8 af[4], bf[4];
                #pragma unroll
                for (int mf = 0; mf < 4; ++mf) af[mf] = *(const bf16x8*)&ga[aoff[mf]];
                #pragma unroll
                for (int nf = 0; nf < 4; ++nf) bf[nf] = *(const bf16x8*)&wb[boff[nf]];
                #pragma unroll
                for (int mf = 0; mf < 4; ++mf)
                    #pragma unroll
                    for (int nf = 0; nf < 4; ++nf)
                        acc[mf][nf] = __builtin_amdgcn_mfma_f32_16x16x32_bf16(
                            af[mf], bf[nf], acc[mf][nf], 0, 0, 0);
            }
        }
    }
    #pragma unroll
    for (int mf = 0; mf < 4; ++mf)
        #pragma unroll
        for (int rr = 0; rr < 4; ++rr) {
            const int P = mtile * 128 + mbase + mf * 16 + q * 4 + rr;
            const int b = P / NPIX;
            const int rem = P % NPIX;
            const int iy = rem / WG, jx = rem % WG;
            const int y = 2 * iy + dy, x = 2 * jx + dx;
            float* orow = out + (size_t)((b * HIN + y) * WIN + x) * Cc + ntile * 128 + nbase + r16;
            #pragma unroll
            for (int nf = 0; nf < 4; ++nf) orow[nf * 16] = acc[mf][nf][rr];
        }
}

__global__ __launch_bounds__(256) void k_grad_wt_fb(
    const float* __restrict__ g, const float* __restrict__ inp, float* __restrict__ gw)
{
    __shared__ unsigned short xa[128 * 64];
    __shared__ unsigned short xg[128 * 64];
    const int t = threadIdx.x;
    const int l = t & 63, wave = t >> 6;
    const int mbase = (wave & 1) * 64, nbase = (wave >> 1) * 64;
    const int q = l >> 4, r16 = l & 15;
    const int tci = (blockIdx.x >> 1) * 128, tco = (blockIdx.x & 1) * 128;
    const int tap = blockIdx.y;
    const int ki = tap / 3, kj = tap % 3;
    const int b = blockIdx.z;
    const int pg = t >> 5, p0 = pg * 8, c4 = (t & 31) * 4;
    f32x4 acc[4][4];
    #pragma unroll
    for (int a = 0; a < 4; ++a)
        #pragma unroll
        for (int c = 0; c < 4; ++c) acc[a][c] = (f32x4){0.f,0.f,0.f,0.f};
    int aoff[2][4], boff[2][4];
    #pragma unroll
    for (int kk = 0; kk < 2; ++kk)
        #pragma unroll
        for (int mf = 0; mf < 4; ++mf) {
            aoff[kk][mf] = swz64(mbase + mf * 16 + r16, kk * 32 + q * 8);
            boff[kk][mf] = swz64(nbase + mf * 16 + r16, kk * 32 + q * 8);
        }
    const float* __restrict__ gb = g + (size_t)b * NPIX * Cc;
    const float* __restrict__ ib = inp + (size_t)b * HIN * WIN * Cc;
    float4 xr[8], gr[8];
    auto load_chunk = [&](int cc) {
        #pragma unroll
        for (int j = 0; j < 8; ++j) {
            const int p = cc * 64 + p0 + j;
            const int i = p / WG, jw = p % WG;
            const int r = ki + 2 * i, s = kj + 2 * jw;
            const bool vx = (p < NPIX) && (r < HIN) && (s < WIN);
            const bool vg = (p < NPIX);
            float4 xv = make_float4(0.f,0.f,0.f,0.f), gv = xv;
            if (vx) xv = *(const float4*)(ib + (size_t)(r * WIN + s) * Cc + tci + c4);
            if (vg) gv = *(const float4*)(gb + (size_t)p * Cc + tco + c4);
            xr[j] = xv; gr[j] = gv;
        }
    };
    load_chunk(0);
    #pragma unroll 1
    for (int cc = 0; cc < 13; ++cc) {
        bf16x8 wx[4], wg[4];
        #pragma unroll
        for (int j = 0; j < 8; ++j) {
            wx[0][j] = (short)f2bf(xr[j].x); wx[1][j] = (short)f2bf(xr[j].y);
            wx[2][j] = (short)f2bf(xr[j].z); wx[3][j] = (short)f2bf(xr[j].w);
            wg[0][j] = (short)f2bf(gr[j].x); wg[1][j] = (short)f2bf(gr[j].y);
            wg[2][j] = (short)f2bf(gr[j].z); wg[3][j] = (short)f2bf(gr[j].w);
        }
        if (cc + 1 < 13) load_chunk(cc + 1);
        lds_barrier();
        #pragma unroll
        for (int c = 0; c < 4; ++c) {
            *(bf16x8*)&xa[swz64(c4 + c, p0)] = wx[c];
            *(bf16x8*)&xg[swz64(c4 + c, p0)] = wg[c];
        }
        lds_barrier();
        #pragma unroll
        for (int kk = 0; kk < 2; ++kk) {
            bf16x8 af[4], bfr[4];
            #pragma unroll
            for (int mf = 0; mf < 4; ++mf) af[mf] = *(const bf16x8*)&xa[aoff[kk][mf]];
            #pragma unroll
            for (int nf = 0; nf < 4; ++nf) bfr[nf] = *(const bf16x8*)&xg[boff[kk][nf]];
            #pragma unroll
            for (int mf = 0; mf < 4; ++mf)
                #pragma unroll
                for (int nf = 0; nf < 4; ++nf)
                    acc[mf][nf] = __builtin_amdgcn_mfma_f32_16x16x32_bf16(
                        af[mf], bfr[nf], acc[mf][nf], 0, 0, 0);
        }
    }
    #pragma unroll
    for (int mf = 0; mf < 4; ++mf)
        #pragma unroll
        for (int rr = 0; rr < 4; ++rr) {
            const int cirow = tci + mbase + mf * 16 + q * 4 + rr;
            float* dst = gw + (size_t)(tap * Cc + cirow) * Cc + tco + nbase + r16;
            #pragma unroll
            for (int nf = 0; nf < 4; ++nf) atomicAdd(dst + nf * 16, acc[mf][nf][rr]);
        }
}

extern "C" void kernel_launch(void* const* d_in, const int* in_sizes, int n_in,
                              void* d_out, int out_size, void* d_ws, size_t ws_size,
                              hipStream_t stream) {
    const float* g   = (const float*)d_in[0];   // grad_output [32,28,28,256]
    const float* inp = (const float*)d_in[1];   // inputs      [32,56,56,256]
    const float* wt  = (const float*)d_in[2];   // kernels     [3,3,256,256]
    float* out = (float*)d_out;

    if (ws_size >= WS_NEED) {
        unsigned short* xt  = (unsigned short*)d_ws;
        unsigned short* gp  = xt + XT_E;
        unsigned short* wtb = gp + GPAD_E;
        k_prep_all <<<NB_ALL, 256, 0, stream>>>(g, inp, wt, xt, gp, wtb, out + GW_OFF);
        k_grad_in_f<<<dim3(196, 2, 4), 256, 0, stream>>>(gp, wtb, out);
        k_grad_wt_f<<<NB_GWTB, 256, 0, stream>>>(xt, gp, out + GW_OFF, out + BIAS_OFF);
    } else {
        const int nzero = GW_SIZE + 256;
        k_zero<<<(nzero + 255) / 256, 256, 0, stream>>>(out + GW_OFF, nzero);
        k_grad_in_fb<<<dim3(196, 2, 4), 256, 0, stream>>>(g, wt, out);
        k_grad_wt_fb<<<dim3(4, 9, 32), 256, 0, stream>>>(g, inp, out + GW_OFF);
        k_bias<<<392, 256, 0, stream>>>(g, out + BIAS_OFF);
    }
}